// Round 5
// baseline (832.553 us; speedup 1.0000x reference)
//
#include <hip/hip_runtime.h>
#include <stdint.h>

#define DD 128
#define NB_G 2048   // k_gather blocks (partials count)

using f32x4  = __attribute__((ext_vector_type(4))) float;
using bf16x8 = __attribute__((ext_vector_type(8))) short;

__device__ __forceinline__ float bf2f(short u) {
  union { unsigned int i; float f; } c;
  c.i = ((unsigned int)(unsigned short)u) << 16;
  return c.f;
}
__device__ __forceinline__ short f2bf(float f) {
  union { float f; unsigned int i; } c;
  c.f = f;
  unsigned int u = c.i;
  u += 0x7fffu + ((u >> 16) & 1u);
  return (short)(u >> 16);
}

// ---------------- CSR build ----------------
__global__ __launch_bounds__(256) void k_hist(const int* __restrict__ dst, int* __restrict__ deg, int E) {
  int e = blockIdx.x * 256 + threadIdx.x;
  if (e < E) atomicAdd(&deg[dst[e]], 1);
}

__global__ __launch_bounds__(256) void k_scan1(const int* __restrict__ deg, int* __restrict__ off,
                                               int* __restrict__ totals, int n) {
  __shared__ int sm[256];
  int t = threadIdx.x;
  int i = blockIdx.x * 256 + t;
  int v = (i < n) ? deg[i] : 0;
  sm[t] = v;
  __syncthreads();
  int acc = v;
  #pragma unroll
  for (int d = 1; d < 256; d <<= 1) {
    int add = (t >= d) ? sm[t - d] : 0;
    __syncthreads();
    acc += add;
    sm[t] = acc;
    __syncthreads();
  }
  if (i < n) off[i] = acc - v;          // exclusive
  if (t == 255) totals[blockIdx.x] = acc;
}

__global__ __launch_bounds__(256) void k_scan2(const int* __restrict__ totals, int* __restrict__ boff, int nb) {
  __shared__ int sm[256];
  int t = threadIdx.x;
  int v = (t < nb) ? totals[t] : 0;
  sm[t] = v;
  __syncthreads();
  int acc = v;
  #pragma unroll
  for (int d = 1; d < 256; d <<= 1) {
    int add = (t >= d) ? sm[t - d] : 0;
    __syncthreads();
    acc += add;
    sm[t] = acc;
    __syncthreads();
  }
  boff[t] = acc - v;
}

__global__ __launch_bounds__(256) void k_scan3(int* __restrict__ off, const int* __restrict__ boff,
                                               int* __restrict__ cursor, int n) {
  int i = blockIdx.x * 256 + threadIdx.x;
  if (i < n) {
    int o = off[i] + boff[blockIdx.x];
    off[i] = o;
    cursor[i] = o;
  }
}

// fill CSR: list (slot -> original edge id), srcS (slot -> src node)
__global__ __launch_bounds__(256) void k_fill(const int* __restrict__ dst, const int* __restrict__ src,
                                              int* __restrict__ cursor, int* __restrict__ list,
                                              int* __restrict__ srcS, int E) {
  int e = blockIdx.x * 256 + threadIdx.x;
  if (e < E) {
    int p = atomicAdd(&cursor[dst[e]], 1);
    list[p] = e;
    srcS[p] = src[e];
  }
}

// ---------------- one-time weight convert+transpose: Wt[c][k] = bf16(W[k][c]) ----------------
__global__ __launch_bounds__(256) void k_prewt5(
    const float* __restrict__ WA, const float* __restrict__ WB, const float* __restrict__ WC,
    const float* __restrict__ WD, const float* __restrict__ WE,
    short* __restrict__ WtA, short* __restrict__ WtB, short* __restrict__ WtC,
    short* __restrict__ WtD, short* __restrict__ WtE) {
  const float* Ws[5] = {WA, WB, WC, WD, WE};
  short* Os[5] = {WtA, WtB, WtC, WtD, WtE};
  const float* W = Ws[blockIdx.x];
  short* O = Os[blockIdx.x];
  int t = threadIdx.x, c = t & 127, h = t >> 7;
  for (int p = 0; p < 8; ++p) {
    int k0 = (h * 8 + p) * 8;
    bf16x8 v;
    #pragma unroll
    for (int j = 0; j < 8; ++j) v[j] = f2bf(W[(size_t)(k0 + j) * DD + c]);
    *(bf16x8*)&O[(size_t)c * DD + k0] = v;
  }
}

// ---------------- node-side GEMMs (swapped MFMA: lane owns one row, 4-feature chunks) ----------
// D = Wt_frag (A) x xrow_frag (B): D[feat][row]; lane(lg,lc): row=m0+w*16+lc,
// feats = tt*16+lg*4..+3 -> bias add + short4 store all register-local, no LDS.
__global__ __launch_bounds__(256) void k_nodegemm(
    const float* __restrict__ x,
    const short* __restrict__ WtA, const float* __restrict__ bA,
    const short* __restrict__ WtB, const float* __restrict__ bB,
    const short* __restrict__ WtD, const float* __restrict__ bD,
    const short* __restrict__ WtE, const float* __restrict__ bE,
    short* __restrict__ Axh, short* __restrict__ Bxh,
    short* __restrict__ Dxh, short* __restrict__ Exh, int n) {
  int t = threadIdx.x;
  int w = t >> 6, l = t & 63, lg = l >> 4, lc = l & 15;
  int m0 = blockIdx.x * 64;
  int row = m0 + w * 16 + lc;
  bool valid = row < n;
  int rowc = valid ? row : n - 1;

  const float* xr = x + (size_t)rowc * DD;
  bf16x8 af[4];
  #pragma unroll
  for (int kk = 0; kk < 4; ++kk) {
    float4 a0 = *(const float4*)&xr[kk * 32 + lg * 8];
    float4 a1 = *(const float4*)&xr[kk * 32 + lg * 8 + 4];
    af[kk][0] = f2bf(a0.x); af[kk][1] = f2bf(a0.y); af[kk][2] = f2bf(a0.z); af[kk][3] = f2bf(a0.w);
    af[kk][4] = f2bf(a1.x); af[kk][5] = f2bf(a1.y); af[kk][6] = f2bf(a1.z); af[kk][7] = f2bf(a1.w);
  }

  const short* Wt[4] = {WtA, WtB, WtD, WtE};
  const float* bs[4] = {bA, bB, bD, bE};
  short* Os[4] = {Axh, Bxh, Dxh, Exh};

  #pragma unroll
  for (int mi = 0; mi < 4; ++mi) {
    const short* Wm = Wt[mi];
    f32x4 acc[8] = {};
    #pragma unroll
    for (int kk = 0; kk < 4; ++kk) {
      #pragma unroll
      for (int tt = 0; tt < 8; ++tt) {
        bf16x8 bfv = *(const bf16x8*)&Wm[(size_t)(tt * 16 + lc) * DD + kk * 32 + lg * 8];
        acc[tt] = __builtin_amdgcn_mfma_f32_16x16x32_bf16(bfv, af[kk], acc[tt], 0, 0, 0);
      }
    }
    if (valid) {
      short* O = Os[mi];
      #pragma unroll
      for (int tt = 0; tt < 8; ++tt) {
        int f0 = tt * 16 + lg * 4;
        float4 bc = *(const float4*)&bs[mi][f0];
        short4 o;
        o.x = f2bf(acc[tt][0] + bc.x);
        o.y = f2bf(acc[tt][1] + bc.y);
        o.z = f2bf(acc[tt][2] + bc.z);
        o.w = f2bf(acc[tt][3] + bc.w);
        *(short4*)&O[(size_t)row * DD + f0] = o;
      }
    }
  }
}

// ---------------- edge kernel: Ce GEMM + Dx[dst]+Ex[src]+bC -> eij (ORIGINAL edge order) ------
// Swapped MFMA: lane owns one edge row; gathers/stores are 8B vector ops; streaming writes.
__global__ __launch_bounds__(256) void k_edge(
    const float* __restrict__ e, const short* __restrict__ WtC, const float* __restrict__ bC,
    const int* __restrict__ srcI, const int* __restrict__ dstI,
    const short* __restrict__ Dxh, const short* __restrict__ Exh,
    short* __restrict__ eij, int Etot) {
  int t = threadIdx.x;
  int w = t >> 6, l = t & 63, lg = l >> 4, lc = l & 15;
  size_t m0 = (size_t)blockIdx.x * 64;
  size_t edge = m0 + w * 16 + lc;
  bool valid = edge < (size_t)Etot;
  size_t edgec = valid ? edge : (size_t)(Etot - 1);

  int dn = dstI[edgec], sn = srcI[edgec];   // issued early; 4 lanes share value

  const float* er = e + edgec * DD;
  bf16x8 af[4];
  #pragma unroll
  for (int kk = 0; kk < 4; ++kk) {
    float4 a0 = *(const float4*)&er[kk * 32 + lg * 8];
    float4 a1 = *(const float4*)&er[kk * 32 + lg * 8 + 4];
    af[kk][0] = f2bf(a0.x); af[kk][1] = f2bf(a0.y); af[kk][2] = f2bf(a0.z); af[kk][3] = f2bf(a0.w);
    af[kk][4] = f2bf(a1.x); af[kk][5] = f2bf(a1.y); af[kk][6] = f2bf(a1.z); af[kk][7] = f2bf(a1.w);
  }

  f32x4 acc[8] = {};
  #pragma unroll
  for (int kk = 0; kk < 4; ++kk) {
    #pragma unroll
    for (int tt = 0; tt < 8; ++tt) {
      bf16x8 bfv = *(const bf16x8*)&WtC[(size_t)(tt * 16 + lc) * DD + kk * 32 + lg * 8];
      acc[tt] = __builtin_amdgcn_mfma_f32_16x16x32_bf16(bfv, af[kk], acc[tt], 0, 0, 0);
    }
  }

  if (valid) {
    const short* dr = Dxh + (size_t)dn * DD;
    const short* sr = Exh + (size_t)sn * DD;
    #pragma unroll
    for (int tt = 0; tt < 8; ++tt) {
      int f0 = tt * 16 + lg * 4;
      float4 bc = *(const float4*)&bC[f0];
      ushort4 dv = *(const ushort4*)&dr[f0];
      ushort4 sv = *(const ushort4*)&sr[f0];
      short4 o;
      o.x = f2bf(acc[tt][0] + bc.x + bf2f((short)dv.x) + bf2f((short)sv.x));
      o.y = f2bf(acc[tt][1] + bc.y + bf2f((short)dv.y) + bf2f((short)sv.y));
      o.z = f2bf(acc[tt][2] + bc.z + bf2f((short)dv.z) + bf2f((short)sv.z));
      o.w = f2bf(acc[tt][3] + bc.w + bf2f((short)dv.w) + bf2f((short)sv.w));
      *(short4*)&eij[edge * DD + f0] = o;
    }
  }
}

// ---------------- gather (wave-per-node via CSR list) + fused stats ----------------
__global__ __launch_bounds__(256) void k_gather(
    const int* __restrict__ off, const int* __restrict__ deg, const int* __restrict__ list,
    const int* __restrict__ srcS, const short* __restrict__ eij, const short* __restrict__ Bxh,
    const short* __restrict__ Axh, float* __restrict__ outx,
    float* __restrict__ pE, float* __restrict__ pX, int n) {
  int t = threadIdx.x;
  int w = t >> 6, l = t & 63;
  int qw = l >> 4, fi = l & 15;
  int waveId = blockIdx.x * 4 + w;
  const int nwaves = NB_G * 4;

  float se[8] = {}, qe[8] = {};
  float sx[4] = {}, qx[4] = {};

  for (int node = waveId; node < n; node += nwaves) {
    int start = off[node], dg = deg[node];
    float num[8] = {}, den[8] = {};
    int k = qw;
    for (; k + 4 < dg; k += 8) {
      int p0 = start + k, p1 = start + k + 4;
      int id0 = list[p0], id1 = list[p1];
      int s0 = srcS[p0], s1 = srcS[p1];
      bf16x8 e0 = *(const bf16x8*)&eij[(size_t)id0 * DD + fi * 8];
      bf16x8 e1 = *(const bf16x8*)&eij[(size_t)id1 * DD + fi * 8];
      bf16x8 b0 = *(const bf16x8*)&Bxh[(size_t)s0 * DD + fi * 8];
      bf16x8 b1 = *(const bf16x8*)&Bxh[(size_t)s1 * DD + fi * 8];
      #pragma unroll
      for (int j = 0; j < 8; ++j) {
        float v0 = bf2f(e0[j]), v1 = bf2f(e1[j]);
        float g0 = 1.f / (1.f + __expf(-v0)), g1 = 1.f / (1.f + __expf(-v1));
        num[j] += g0 * bf2f(b0[j]) + g1 * bf2f(b1[j]);
        den[j] += g0 + g1;
        se[j] += v0 + v1; qe[j] += v0 * v0 + v1 * v1;
      }
    }
    for (; k < dg; k += 4) {
      int p0 = start + k;
      int id0 = list[p0];
      int s0 = srcS[p0];
      bf16x8 e0 = *(const bf16x8*)&eij[(size_t)id0 * DD + fi * 8];
      bf16x8 b0 = *(const bf16x8*)&Bxh[(size_t)s0 * DD + fi * 8];
      #pragma unroll
      for (int j = 0; j < 8; ++j) {
        float v0 = bf2f(e0[j]);
        float g0 = 1.f / (1.f + __expf(-v0));
        num[j] += g0 * bf2f(b0[j]);
        den[j] += g0;
        se[j] += v0; qe[j] += v0 * v0;
      }
    }
    #pragma unroll
    for (int j = 0; j < 8; ++j) {
      num[j] += __shfl_xor(num[j], 16); num[j] += __shfl_xor(num[j], 32);
      den[j] += __shfl_xor(den[j], 16); den[j] += __shfl_xor(den[j], 32);
    }
    if (qw < 2) {
      int c0 = fi * 8 + qw * 4;
      short4 ax = *(const short4*)&Axh[(size_t)node * DD + c0];
      short axa[4] = {ax.x, ax.y, ax.z, ax.w};
      float4 o;
      float vv[4];
      #pragma unroll
      for (int j = 0; j < 4; ++j) {
        int jj = qw * 4 + j;
        float aggr = num[jj] / (den[jj] + 1e-6f);
        float xp = bf2f(axa[j]) + aggr;
        vv[j] = xp;
        sx[j] += xp; qx[j] += xp * xp;
      }
      o.x = vv[0]; o.y = vv[1]; o.z = vv[2]; o.w = vv[3];
      *(float4*)&outx[(size_t)node * DD + c0] = o;
    }
  }

  #pragma unroll
  for (int j = 0; j < 8; ++j) {
    se[j] += __shfl_xor(se[j], 16); se[j] += __shfl_xor(se[j], 32);
    qe[j] += __shfl_xor(qe[j], 16); qe[j] += __shfl_xor(qe[j], 32);
  }
  __shared__ float lsE[4][128], lqE[4][128], lsX[4][128], lqX[4][128];
  if (qw == 0) {
    #pragma unroll
    for (int j = 0; j < 8; ++j) { lsE[w][fi * 8 + j] = se[j]; lqE[w][fi * 8 + j] = qe[j]; }
  }
  if (qw < 2) {
    #pragma unroll
    for (int j = 0; j < 4; ++j) { lsX[w][fi * 8 + qw * 4 + j] = sx[j]; lqX[w][fi * 8 + qw * 4 + j] = qx[j]; }
  }
  __syncthreads();
  if (t < 128) {
    float a = lsE[0][t] + lsE[1][t] + lsE[2][t] + lsE[3][t];
    float b = lqE[0][t] + lqE[1][t] + lqE[2][t] + lqE[3][t];
    pE[(size_t)blockIdx.x * 256 + t] = a;
    pE[(size_t)blockIdx.x * 256 + 128 + t] = b;
  } else {
    int c = t - 128;
    float a = lsX[0][c] + lsX[1][c] + lsX[2][c] + lsX[3][c];
    float b = lqX[0][c] + lqX[1][c] + lqX[2][c] + lqX[3][c];
    pX[(size_t)blockIdx.x * 256 + c] = a;
    pX[(size_t)blockIdx.x * 256 + 128 + c] = b;
  }
}

// reduce partials -> folded BN affine: stats[c]=scale, stats[128+c]=shift
__global__ __launch_bounds__(256) void k_reduce(const float* __restrict__ part, int nblk, float invcnt,
                                                const float* __restrict__ gamma, const float* __restrict__ beta,
                                                float* __restrict__ stats) {
  int c = blockIdx.x, t = threadIdx.x;
  float a = 0.f, b = 0.f;
  for (int k = t; k < nblk; k += 256) {
    a += part[(size_t)k * 256 + c];
    b += part[(size_t)k * 256 + 128 + c];
  }
  #pragma unroll
  for (int o = 32; o > 0; o >>= 1) { a += __shfl_down(a, o); b += __shfl_down(b, o); }
  __shared__ float ra[4], rb[4];
  int l = t & 63, w = t >> 6;
  if (l == 0) { ra[w] = a; rb[w] = b; }
  __syncthreads();
  if (t == 0) {
    a = ra[0] + ra[1] + ra[2] + ra[3];
    b = rb[0] + rb[1] + rb[2] + rb[3];
    float mean = a * invcnt;
    float var = b * invcnt - mean * mean;   // biased variance
    float istd = rsqrtf(var + 1e-5f);
    float scale = gamma[c] * istd;
    stats[c] = scale;
    stats[128 + c] = beta[c] - mean * scale;
  }
}

// ---------------- finalize ----------------
__global__ __launch_bounds__(256) void k_xfinal(float* __restrict__ v, const float* __restrict__ st, size_t n4) {
  size_t i = (size_t)blockIdx.x * 256 + threadIdx.x;
  if (i >= n4) return;
  float4 d = *(const float4*)&v[i * 4];
  int f0 = (int)((i * 4) & 127);
  d.x = fmaxf(0.f, d.x * st[f0 + 0] + st[128 + f0 + 0]);
  d.y = fmaxf(0.f, d.y * st[f0 + 1] + st[128 + f0 + 1]);
  d.z = fmaxf(0.f, d.z * st[f0 + 2] + st[128 + f0 + 2]);
  d.w = fmaxf(0.f, d.w * st[f0 + 3] + st[128 + f0 + 3]);
  *(float4*)&v[i * 4] = d;
}

// pure streaming: sequential read of eij (original order) -> BN+ReLU -> sequential write
__global__ __launch_bounds__(256) void k_efinal(const short* __restrict__ eij, const float* __restrict__ st,
                                                float* __restrict__ out, size_t n8) {
  size_t i = (size_t)blockIdx.x * 256 + threadIdx.x;
  if (i >= n8) return;
  bf16x8 u = *(const bf16x8*)&eij[i * 8];
  int f0 = (int)((i * 8) & 127);
  float4 s0 = *(const float4*)&st[f0], s1 = *(const float4*)&st[f0 + 4];
  float4 h0 = *(const float4*)&st[128 + f0], h1 = *(const float4*)&st[128 + f0 + 4];
  float4 a, b;
  a.x = fmaxf(0.f, bf2f(u[0]) * s0.x + h0.x);
  a.y = fmaxf(0.f, bf2f(u[1]) * s0.y + h0.y);
  a.z = fmaxf(0.f, bf2f(u[2]) * s0.z + h0.z);
  a.w = fmaxf(0.f, bf2f(u[3]) * s0.w + h0.w);
  b.x = fmaxf(0.f, bf2f(u[4]) * s1.x + h1.x);
  b.y = fmaxf(0.f, bf2f(u[5]) * s1.y + h1.y);
  b.z = fmaxf(0.f, bf2f(u[6]) * s1.z + h1.z);
  b.w = fmaxf(0.f, bf2f(u[7]) * s1.w + h1.w);
  *(float4*)&out[i * 8] = a;
  *(float4*)&out[i * 8 + 4] = b;
}

extern "C" void kernel_launch(void* const* d_in, const int* in_sizes, int n_in,
                              void* d_out, int out_size, void* d_ws, size_t ws_size,
                              hipStream_t stream) {
  const float* x  = (const float*)d_in[0];
  const float* e  = (const float*)d_in[1];
  const int*   ei = (const int*)d_in[2];
  const float* WA = (const float*)d_in[3];  const float* bA = (const float*)d_in[4];
  const float* WB = (const float*)d_in[5];  const float* bB = (const float*)d_in[6];
  const float* WC = (const float*)d_in[7];  const float* bC = (const float*)d_in[8];
  const float* WD = (const float*)d_in[9];  const float* bD = (const float*)d_in[10];
  const float* WE = (const float*)d_in[11]; const float* bE = (const float*)d_in[12];
  const float* gx = (const float*)d_in[13]; const float* bx = (const float*)d_in[14];
  const float* ge = (const float*)d_in[15]; const float* be = (const float*)d_in[16];

  int N = in_sizes[0] / DD;
  int E = in_sizes[2] / 2;
  const int* srcI = ei;       // edge_index[0]
  const int* dstI = ei + E;   // edge_index[1]

  float* outx = (float*)d_out;
  float* oute = (float*)d_out + (size_t)N * DD;

  char* wp = (char*)d_ws;
  auto alloc = [&](size_t sz) { char* p = wp; wp += (sz + 255) & ~(size_t)255; return p; };
  short* Axh    = (short*)alloc((size_t)N * DD * 2);
  short* Bxh    = (short*)alloc((size_t)N * DD * 2);
  short* Dxh    = (short*)alloc((size_t)N * DD * 2);
  short* Exh    = (short*)alloc((size_t)N * DD * 2);
  short* eij    = (short*)alloc((size_t)E * DD * 2);
  int*   deg    = (int*)alloc((size_t)N * 4);
  int*   off    = (int*)alloc((size_t)N * 4);
  int*   cursor = (int*)alloc((size_t)N * 4);
  int*   totals = (int*)alloc(1024);
  int*   boff   = (int*)alloc(1024);
  int*   list   = (int*)alloc((size_t)E * 4);
  int*   srcS   = (int*)alloc((size_t)E * 4);
  float* pE     = (float*)alloc((size_t)NB_G * 256 * 4);
  float* pX     = (float*)alloc((size_t)NB_G * 256 * 4);
  float* statsE = (float*)alloc(1024);
  float* statsX = (float*)alloc(1024);
  short* WtA    = (short*)alloc((size_t)DD * DD * 2);
  short* WtB    = (short*)alloc((size_t)DD * DD * 2);
  short* WtC    = (short*)alloc((size_t)DD * DD * 2);
  short* WtD    = (short*)alloc((size_t)DD * DD * 2);
  short* WtE    = (short*)alloc((size_t)DD * DD * 2);
  (void)ws_size; (void)n_in; (void)out_size;

  int nsb = (N + 255) / 256;

  hipMemsetAsync(deg, 0, (size_t)N * 4, stream);
  k_prewt5<<<5, 256, 0, stream>>>(WA, WB, WC, WD, WE, WtA, WtB, WtC, WtD, WtE);
  k_hist<<<(E + 255) / 256, 256, 0, stream>>>(dstI, deg, E);
  k_scan1<<<nsb, 256, 0, stream>>>(deg, off, totals, N);
  k_scan2<<<1, 256, 0, stream>>>(totals, boff, nsb);
  k_scan3<<<nsb, 256, 0, stream>>>(off, boff, cursor, N);
  k_fill<<<(E + 255) / 256, 256, 0, stream>>>(dstI, srcI, cursor, list, srcS, E);

  k_nodegemm<<<(N + 63) / 64, 256, 0, stream>>>(x, WtA, bA, WtB, bB, WtD, bD, WtE, bE,
                                                Axh, Bxh, Dxh, Exh, N);
  k_edge<<<(E + 63) / 64, 256, 0, stream>>>(e, WtC, bC, srcI, dstI, Dxh, Exh, eij, E);

  k_gather<<<NB_G, 256, 0, stream>>>(off, deg, list, srcS, eij, Bxh, Axh, outx, pE, pX, N);
  k_reduce<<<128, 256, 0, stream>>>(pE, NB_G, 1.0f / (float)E, ge, be, statsE);
  k_reduce<<<128, 256, 0, stream>>>(pX, NB_G, 1.0f / (float)N, gx, bx, statsX);

  k_xfinal<<<(int)(((size_t)N * DD / 4 + 255) / 256), 256, 0, stream>>>(outx, statsX, (size_t)N * DD / 4);
  k_efinal<<<(int)(((size_t)E * DD / 8 + 255) / 256), 256, 0, stream>>>(eij, statsE, oute, (size_t)E * DD / 8);
}

// Round 6
// 694.934 us; speedup vs baseline: 1.1980x; 1.1980x over previous
//
#include <hip/hip_runtime.h>
#include <stdint.h>

#define DD 128
#define NB_G 2048   // k_gather blocks (partials count)

using f32x4  = __attribute__((ext_vector_type(4))) float;
using bf16x8 = __attribute__((ext_vector_type(8))) short;

__device__ __forceinline__ float bf2f(short u) {
  union { unsigned int i; float f; } c;
  c.i = ((unsigned int)(unsigned short)u) << 16;
  return c.f;
}
__device__ __forceinline__ short f2bf(float f) {
  union { float f; unsigned int i; } c;
  c.f = f;
  unsigned int u = c.i;
  u += 0x7fffu + ((u >> 16) & 1u);
  return (short)(u >> 16);
}

// ---------------- CSR build ----------------
__global__ __launch_bounds__(256) void k_hist(const int* __restrict__ dst, int* __restrict__ deg, int E) {
  int e = blockIdx.x * 256 + threadIdx.x;
  if (e < E) atomicAdd(&deg[dst[e]], 1);
}

__global__ __launch_bounds__(256) void k_scan1(const int* __restrict__ deg, int* __restrict__ off,
                                               int* __restrict__ totals, int n) {
  __shared__ int sm[256];
  int t = threadIdx.x;
  int i = blockIdx.x * 256 + t;
  int v = (i < n) ? deg[i] : 0;
  sm[t] = v;
  __syncthreads();
  int acc = v;
  #pragma unroll
  for (int d = 1; d < 256; d <<= 1) {
    int add = (t >= d) ? sm[t - d] : 0;
    __syncthreads();
    acc += add;
    sm[t] = acc;
    __syncthreads();
  }
  if (i < n) off[i] = acc - v;          // exclusive
  if (t == 255) totals[blockIdx.x] = acc;
}

__global__ __launch_bounds__(256) void k_scan2(const int* __restrict__ totals, int* __restrict__ boff, int nb) {
  __shared__ int sm[256];
  int t = threadIdx.x;
  int v = (t < nb) ? totals[t] : 0;
  sm[t] = v;
  __syncthreads();
  int acc = v;
  #pragma unroll
  for (int d = 1; d < 256; d <<= 1) {
    int add = (t >= d) ? sm[t - d] : 0;
    __syncthreads();
    acc += add;
    sm[t] = acc;
    __syncthreads();
  }
  boff[t] = acc - v;
}

__global__ __launch_bounds__(256) void k_scan3(int* __restrict__ off, const int* __restrict__ boff,
                                               int* __restrict__ cursor, int n) {
  int i = blockIdx.x * 256 + threadIdx.x;
  if (i < n) {
    int o = off[i] + boff[blockIdx.x];
    off[i] = o;
    cursor[i] = o;
  }
}

// fill CSR: list (slot -> original edge id), srcS (slot -> src node)
__global__ __launch_bounds__(256) void k_fill(const int* __restrict__ dst, const int* __restrict__ src,
                                              int* __restrict__ cursor, int* __restrict__ list,
                                              int* __restrict__ srcS, int E) {
  int e = blockIdx.x * 256 + threadIdx.x;
  if (e < E) {
    int p = atomicAdd(&cursor[dst[e]], 1);
    list[p] = e;
    srcS[p] = src[e];
  }
}

// ---------------- one-time weight convert+transpose: Wt[c][k] = bf16(W[k][c]) ----------------
__global__ __launch_bounds__(256) void k_prewt5(
    const float* __restrict__ WA, const float* __restrict__ WB, const float* __restrict__ WC,
    const float* __restrict__ WD, const float* __restrict__ WE,
    short* __restrict__ WtA, short* __restrict__ WtB, short* __restrict__ WtC,
    short* __restrict__ WtD, short* __restrict__ WtE) {
  const float* Ws[5] = {WA, WB, WC, WD, WE};
  short* Os[5] = {WtA, WtB, WtC, WtD, WtE};
  const float* W = Ws[blockIdx.x];
  short* O = Os[blockIdx.x];
  int t = threadIdx.x, c = t & 127, h = t >> 7;
  for (int p = 0; p < 8; ++p) {
    int k0 = (h * 8 + p) * 8;
    bf16x8 v;
    #pragma unroll
    for (int j = 0; j < 8; ++j) v[j] = f2bf(W[(size_t)(k0 + j) * DD + c]);
    *(bf16x8*)&O[(size_t)c * DD + k0] = v;
  }
}

// ---------------- node-side GEMMs (swapped MFMA; register-local epilogue) ----------
__global__ __launch_bounds__(256) void k_nodegemm(
    const float* __restrict__ x,
    const short* __restrict__ WtA, const float* __restrict__ bA,
    const short* __restrict__ WtB, const float* __restrict__ bB,
    const short* __restrict__ WtD, const float* __restrict__ bD,
    const short* __restrict__ WtE, const float* __restrict__ bE,
    short* __restrict__ Axh, short* __restrict__ Bxh,
    short* __restrict__ Dxh, short* __restrict__ Exh, int n) {
  int t = threadIdx.x;
  int w = t >> 6, l = t & 63, lg = l >> 4, lc = l & 15;
  int m0 = blockIdx.x * 64;
  int row = m0 + w * 16 + lc;
  bool valid = row < n;
  int rowc = valid ? row : n - 1;

  const float* xr = x + (size_t)rowc * DD;
  bf16x8 af[4];
  #pragma unroll
  for (int kk = 0; kk < 4; ++kk) {
    float4 a0 = *(const float4*)&xr[kk * 32 + lg * 8];
    float4 a1 = *(const float4*)&xr[kk * 32 + lg * 8 + 4];
    af[kk][0] = f2bf(a0.x); af[kk][1] = f2bf(a0.y); af[kk][2] = f2bf(a0.z); af[kk][3] = f2bf(a0.w);
    af[kk][4] = f2bf(a1.x); af[kk][5] = f2bf(a1.y); af[kk][6] = f2bf(a1.z); af[kk][7] = f2bf(a1.w);
  }

  const short* Wt[4] = {WtA, WtB, WtD, WtE};
  const float* bs[4] = {bA, bB, bD, bE};
  short* Os[4] = {Axh, Bxh, Dxh, Exh};

  #pragma unroll
  for (int mi = 0; mi < 4; ++mi) {
    const short* Wm = Wt[mi];
    f32x4 acc[8] = {};
    #pragma unroll
    for (int kk = 0; kk < 4; ++kk) {
      #pragma unroll
      for (int tt = 0; tt < 8; ++tt) {
        bf16x8 bfv = *(const bf16x8*)&Wm[(size_t)(tt * 16 + lc) * DD + kk * 32 + lg * 8];
        acc[tt] = __builtin_amdgcn_mfma_f32_16x16x32_bf16(bfv, af[kk], acc[tt], 0, 0, 0);
      }
    }
    if (valid) {
      short* O = Os[mi];
      #pragma unroll
      for (int tt = 0; tt < 8; ++tt) {
        int f0 = tt * 16 + lg * 4;
        float4 bc = *(const float4*)&bs[mi][f0];
        short4 o;
        o.x = f2bf(acc[tt][0] + bc.x);
        o.y = f2bf(acc[tt][1] + bc.y);
        o.z = f2bf(acc[tt][2] + bc.z);
        o.w = f2bf(acc[tt][3] + bc.w);
        *(short4*)&O[(size_t)row * DD + f0] = o;
      }
    }
  }
}

// ---------------- edge kernel: Ce GEMM + Dx[dst]+Ex[src]+bC -> eij (original order) ----------
// Normal-orientation MFMA + per-wave LDS restage (1KB-contiguous stores).
// Dx/Ex row gathers hoisted to kernel top (overlap with e-loads + MFMA).
// Also accumulates per-block e-stat partials (sum, sumsq per feature).
__global__ __launch_bounds__(256) void k_edge(
    const float* __restrict__ e, const short* __restrict__ WtC, const float* __restrict__ bC,
    const int* __restrict__ srcI, const int* __restrict__ dstI,
    const short* __restrict__ Dxh, const short* __restrict__ Exh,
    short* __restrict__ eij, float* __restrict__ pE, int Etot) {
  __shared__ __align__(16) short es[4][16][136];   // per-wave private restage
  __shared__ float sE[4][128], qE[4][128];
  int t = threadIdx.x;
  int w = t >> 6, l = t & 63, lg = l >> 4, lc = l & 15;
  size_t m0 = (size_t)blockIdx.x * 64;

  // ---- hoisted: epilogue-row indices + Dx/Ex row gathers (rows z*4+lg, cols lc*8..+7)
  bf16x8 dv[4], sv[4];
  bool vz[4];
  #pragma unroll
  for (int z = 0; z < 4; ++z) {
    size_t erow = m0 + w * 16 + z * 4 + lg;
    vz[z] = erow < (size_t)Etot;
    size_t erc = vz[z] ? erow : (size_t)(Etot - 1);
    int dn = dstI[erc], sn = srcI[erc];
    dv[z] = *(const bf16x8*)&Dxh[(size_t)dn * DD + lc * 8];
    sv[z] = *(const bf16x8*)&Exh[(size_t)sn * DD + lc * 8];
  }

  // ---- A fragments: this lane's MFMA row is m0 + w*16 + lc
  size_t row = m0 + w * 16 + lc;
  size_t rowc = row < (size_t)Etot ? row : (size_t)(Etot - 1);
  const float* er = e + rowc * DD;
  bf16x8 af[4];
  #pragma unroll
  for (int kk = 0; kk < 4; ++kk) {
    float4 a0 = *(const float4*)&er[kk * 32 + lg * 8];
    float4 a1 = *(const float4*)&er[kk * 32 + lg * 8 + 4];
    af[kk][0] = f2bf(a0.x); af[kk][1] = f2bf(a0.y); af[kk][2] = f2bf(a0.z); af[kk][3] = f2bf(a0.w);
    af[kk][4] = f2bf(a1.x); af[kk][5] = f2bf(a1.y); af[kk][6] = f2bf(a1.z); af[kk][7] = f2bf(a1.w);
  }

  f32x4 acc[8] = {};
  #pragma unroll
  for (int kk = 0; kk < 4; ++kk) {
    #pragma unroll
    for (int tt = 0; tt < 8; ++tt) {
      bf16x8 bfv = *(const bf16x8*)&WtC[(size_t)(tt * 16 + lc) * DD + kk * 32 + lg * 8];
      acc[tt] = __builtin_amdgcn_mfma_f32_16x16x32_bf16(af[kk], bfv, acc[tt], 0, 0, 0);
    }
  }

  float bCv[8];
  #pragma unroll
  for (int tt = 0; tt < 8; ++tt) bCv[tt] = bC[tt * 16 + lc];

  // restage Ce+bC: acc[tt][j] = D[row=lg*4+j][col=tt*16+lc]
  #pragma unroll
  for (int tt = 0; tt < 8; ++tt) {
    int col = tt * 16 + lc;
    #pragma unroll
    for (int j = 0; j < 4; ++j)
      es[w][lg * 4 + j][col] = f2bf(acc[tt][j] + bCv[tt]);
  }
  asm volatile("s_waitcnt lgkmcnt(0)" ::: "memory");
  __builtin_amdgcn_sched_barrier(0);

  // epilogue: rows z*4+lg, full wave covers 4 consecutive rows per z (1KB store)
  float se[8] = {}, qe[8] = {};
  #pragma unroll
  for (int z = 0; z < 4; ++z) {
    if (vz[z]) {
      int r = z * 4 + lg;
      size_t erow = m0 + w * 16 + r;
      bf16x8 cv = *(const bf16x8*)&es[w][r][lc * 8];
      bf16x8 o;
      #pragma unroll
      for (int j = 0; j < 8; ++j) {
        float v = bf2f(cv[j]) + bf2f(dv[z][j]) + bf2f(sv[z][j]);
        se[j] += v; qe[j] += v * v;
        o[j] = f2bf(v);
      }
      *(bf16x8*)&eij[erow * DD + lc * 8] = o;
    }
  }
  __builtin_amdgcn_sched_barrier(0);

  // stat reduce: lane cols = lc*8+j; sum over lg groups (xor 16, 32)
  #pragma unroll
  for (int j = 0; j < 8; ++j) {
    se[j] += __shfl_xor(se[j], 16); se[j] += __shfl_xor(se[j], 32);
    qe[j] += __shfl_xor(qe[j], 16); qe[j] += __shfl_xor(qe[j], 32);
  }
  if (lg == 0) {
    #pragma unroll
    for (int j = 0; j < 8; ++j) { sE[w][lc * 8 + j] = se[j]; qE[w][lc * 8 + j] = qe[j]; }
  }
  __syncthreads();
  if (t < 128) {
    float a = sE[0][t] + sE[1][t] + sE[2][t] + sE[3][t];
    float b = qE[0][t] + qE[1][t] + qE[2][t] + qE[3][t];
    pE[(size_t)blockIdx.x * 256 + t] = a;
    pE[(size_t)blockIdx.x * 256 + 128 + t] = b;
  }
}

// ---------------- gather + x_pre + fused e_out write (BN via precomputed statsE) -------------
__global__ __launch_bounds__(256) void k_gather(
    const int* __restrict__ off, const int* __restrict__ deg, const int* __restrict__ list,
    const int* __restrict__ srcS, const short* __restrict__ eij, const short* __restrict__ Bxh,
    const short* __restrict__ Axh, const float* __restrict__ stE,
    float* __restrict__ outx, float* __restrict__ oute,
    float* __restrict__ pX, int n) {
  int t = threadIdx.x;
  int w = t >> 6, l = t & 63;
  int qw = l >> 4, fi = l & 15;
  int waveId = blockIdx.x * 4 + w;
  const int nwaves = NB_G * 4;

  // BN affine for this lane's 8 e-columns
  float su[8], hu[8];
  {
    float4 s0 = *(const float4*)&stE[fi * 8], s1 = *(const float4*)&stE[fi * 8 + 4];
    float4 h0 = *(const float4*)&stE[128 + fi * 8], h1 = *(const float4*)&stE[128 + fi * 8 + 4];
    su[0] = s0.x; su[1] = s0.y; su[2] = s0.z; su[3] = s0.w;
    su[4] = s1.x; su[5] = s1.y; su[6] = s1.z; su[7] = s1.w;
    hu[0] = h0.x; hu[1] = h0.y; hu[2] = h0.z; hu[3] = h0.w;
    hu[4] = h1.x; hu[5] = h1.y; hu[6] = h1.z; hu[7] = h1.w;
  }

  float sx[4] = {}, qx[4] = {};

  for (int node = waveId; node < n; node += nwaves) {
    int start = off[node], dg = deg[node];
    float num[8] = {}, den[8] = {};
    int k = qw;
    for (; k + 4 < dg; k += 8) {
      int p0 = start + k, p1 = start + k + 4;
      int id0 = list[p0], id1 = list[p1];
      int s0 = srcS[p0], s1 = srcS[p1];
      bf16x8 e0 = *(const bf16x8*)&eij[(size_t)id0 * DD + fi * 8];
      bf16x8 e1 = *(const bf16x8*)&eij[(size_t)id1 * DD + fi * 8];
      bf16x8 b0 = *(const bf16x8*)&Bxh[(size_t)s0 * DD + fi * 8];
      bf16x8 b1 = *(const bf16x8*)&Bxh[(size_t)s1 * DD + fi * 8];
      float4 oa, ob, oc, od;
      float v0a[8], v1a[8];
      #pragma unroll
      for (int j = 0; j < 8; ++j) {
        float v0 = bf2f(e0[j]), v1 = bf2f(e1[j]);
        v0a[j] = fmaxf(0.f, v0 * su[j] + hu[j]);
        v1a[j] = fmaxf(0.f, v1 * su[j] + hu[j]);
        float g0 = 1.f / (1.f + __expf(-v0)), g1 = 1.f / (1.f + __expf(-v1));
        num[j] += g0 * bf2f(b0[j]) + g1 * bf2f(b1[j]);
        den[j] += g0 + g1;
      }
      oa.x = v0a[0]; oa.y = v0a[1]; oa.z = v0a[2]; oa.w = v0a[3];
      ob.x = v0a[4]; ob.y = v0a[5]; ob.z = v0a[6]; ob.w = v0a[7];
      oc.x = v1a[0]; oc.y = v1a[1]; oc.z = v1a[2]; oc.w = v1a[3];
      od.x = v1a[4]; od.y = v1a[5]; od.z = v1a[6]; od.w = v1a[7];
      *(float4*)&oute[(size_t)id0 * DD + fi * 8] = oa;
      *(float4*)&oute[(size_t)id0 * DD + fi * 8 + 4] = ob;
      *(float4*)&oute[(size_t)id1 * DD + fi * 8] = oc;
      *(float4*)&oute[(size_t)id1 * DD + fi * 8 + 4] = od;
    }
    for (; k < dg; k += 4) {
      int p0 = start + k;
      int id0 = list[p0];
      int s0 = srcS[p0];
      bf16x8 e0 = *(const bf16x8*)&eij[(size_t)id0 * DD + fi * 8];
      bf16x8 b0 = *(const bf16x8*)&Bxh[(size_t)s0 * DD + fi * 8];
      float4 oa, ob;
      float v0a[8];
      #pragma unroll
      for (int j = 0; j < 8; ++j) {
        float v0 = bf2f(e0[j]);
        v0a[j] = fmaxf(0.f, v0 * su[j] + hu[j]);
        float g0 = 1.f / (1.f + __expf(-v0));
        num[j] += g0 * bf2f(b0[j]);
        den[j] += g0;
      }
      oa.x = v0a[0]; oa.y = v0a[1]; oa.z = v0a[2]; oa.w = v0a[3];
      ob.x = v0a[4]; ob.y = v0a[5]; ob.z = v0a[6]; ob.w = v0a[7];
      *(float4*)&oute[(size_t)id0 * DD + fi * 8] = oa;
      *(float4*)&oute[(size_t)id0 * DD + fi * 8 + 4] = ob;
    }
    #pragma unroll
    for (int j = 0; j < 8; ++j) {
      num[j] += __shfl_xor(num[j], 16); num[j] += __shfl_xor(num[j], 32);
      den[j] += __shfl_xor(den[j], 16); den[j] += __shfl_xor(den[j], 32);
    }
    if (qw < 2) {
      int c0 = fi * 8 + qw * 4;
      short4 ax = *(const short4*)&Axh[(size_t)node * DD + c0];
      short axa[4] = {ax.x, ax.y, ax.z, ax.w};
      float4 o;
      float vv[4];
      #pragma unroll
      for (int j = 0; j < 4; ++j) {
        int jj = qw * 4 + j;
        float aggr = num[jj] / (den[jj] + 1e-6f);
        float xp = bf2f(axa[j]) + aggr;
        vv[j] = xp;
        sx[j] += xp; qx[j] += xp * xp;
      }
      o.x = vv[0]; o.y = vv[1]; o.z = vv[2]; o.w = vv[3];
      *(float4*)&outx[(size_t)node * DD + c0] = o;
    }
  }

  __shared__ float lsX[4][128], lqX[4][128];
  if (qw < 2) {
    #pragma unroll
    for (int j = 0; j < 4; ++j) { lsX[w][fi * 8 + qw * 4 + j] = sx[j]; lqX[w][fi * 8 + qw * 4 + j] = qx[j]; }
  }
  __syncthreads();
  if (t < 128) {
    float a = lsX[0][t] + lsX[1][t] + lsX[2][t] + lsX[3][t];
    float b = lqX[0][t] + lqX[1][t] + lqX[2][t] + lqX[3][t];
    pX[(size_t)blockIdx.x * 256 + t] = a;
    pX[(size_t)blockIdx.x * 256 + 128 + t] = b;
  }
}

// reduce partials -> folded BN affine: stats[c]=scale, stats[128+c]=shift
__global__ __launch_bounds__(256) void k_reduce(const float* __restrict__ part, int nblk, float invcnt,
                                                const float* __restrict__ gamma, const float* __restrict__ beta,
                                                float* __restrict__ stats) {
  int c = blockIdx.x, t = threadIdx.x;
  float a = 0.f, b = 0.f;
  for (int k = t; k < nblk; k += 256) {
    a += part[(size_t)k * 256 + c];
    b += part[(size_t)k * 256 + 128 + c];
  }
  #pragma unroll
  for (int o = 32; o > 0; o >>= 1) { a += __shfl_down(a, o); b += __shfl_down(b, o); }
  __shared__ float ra[4], rb[4];
  int l = t & 63, w = t >> 6;
  if (l == 0) { ra[w] = a; rb[w] = b; }
  __syncthreads();
  if (t == 0) {
    a = ra[0] + ra[1] + ra[2] + ra[3];
    b = rb[0] + rb[1] + rb[2] + rb[3];
    float mean = a * invcnt;
    float var = b * invcnt - mean * mean;   // biased variance
    float istd = rsqrtf(var + 1e-5f);
    float scale = gamma[c] * istd;
    stats[c] = scale;
    stats[128 + c] = beta[c] - mean * scale;
  }
}

// ---------------- finalize x ----------------
__global__ __launch_bounds__(256) void k_xfinal(float* __restrict__ v, const float* __restrict__ st, size_t n4) {
  size_t i = (size_t)blockIdx.x * 256 + threadIdx.x;
  if (i >= n4) return;
  float4 d = *(const float4*)&v[i * 4];
  int f0 = (int)((i * 4) & 127);
  d.x = fmaxf(0.f, d.x * st[f0 + 0] + st[128 + f0 + 0]);
  d.y = fmaxf(0.f, d.y * st[f0 + 1] + st[128 + f0 + 1]);
  d.z = fmaxf(0.f, d.z * st[f0 + 2] + st[128 + f0 + 2]);
  d.w = fmaxf(0.f, d.w * st[f0 + 3] + st[128 + f0 + 3]);
  *(float4*)&v[i * 4] = d;
}

extern "C" void kernel_launch(void* const* d_in, const int* in_sizes, int n_in,
                              void* d_out, int out_size, void* d_ws, size_t ws_size,
                              hipStream_t stream) {
  const float* x  = (const float*)d_in[0];
  const float* e  = (const float*)d_in[1];
  const int*   ei = (const int*)d_in[2];
  const float* WA = (const float*)d_in[3];  const float* bA = (const float*)d_in[4];
  const float* WB = (const float*)d_in[5];  const float* bB = (const float*)d_in[6];
  const float* WC = (const float*)d_in[7];  const float* bC = (const float*)d_in[8];
  const float* WD = (const float*)d_in[9];  const float* bD = (const float*)d_in[10];
  const float* WE = (const float*)d_in[11]; const float* bE = (const float*)d_in[12];
  const float* gx = (const float*)d_in[13]; const float* bx = (const float*)d_in[14];
  const float* ge = (const float*)d_in[15]; const float* be = (const float*)d_in[16];

  int N = in_sizes[0] / DD;
  int E = in_sizes[2] / 2;
  const int* srcI = ei;       // edge_index[0]
  const int* dstI = ei + E;   // edge_index[1]

  float* outx = (float*)d_out;
  float* oute = (float*)d_out + (size_t)N * DD;

  int ntilesE = (E + 63) / 64;

  char* wp = (char*)d_ws;
  auto alloc = [&](size_t sz) { char* p = wp; wp += (sz + 255) & ~(size_t)255; return p; };
  short* Axh    = (short*)alloc((size_t)N * DD * 2);
  short* Bxh    = (short*)alloc((size_t)N * DD * 2);
  short* Dxh    = (short*)alloc((size_t)N * DD * 2);
  short* Exh    = (short*)alloc((size_t)N * DD * 2);
  short* eij    = (short*)alloc((size_t)E * DD * 2);
  int*   deg    = (int*)alloc((size_t)N * 4);
  int*   off    = (int*)alloc((size_t)N * 4);
  int*   cursor = (int*)alloc((size_t)N * 4);
  int*   totals = (int*)alloc(1024);
  int*   boff   = (int*)alloc(1024);
  int*   list   = (int*)alloc((size_t)E * 4);
  int*   srcS   = (int*)alloc((size_t)E * 4);
  float* pE     = (float*)alloc((size_t)ntilesE * 256 * 4);
  float* pX     = (float*)alloc((size_t)NB_G * 256 * 4);
  float* statsE = (float*)alloc(1024);
  float* statsX = (float*)alloc(1024);
  short* WtA    = (short*)alloc((size_t)DD * DD * 2);
  short* WtB    = (short*)alloc((size_t)DD * DD * 2);
  short* WtC    = (short*)alloc((size_t)DD * DD * 2);
  short* WtD    = (short*)alloc((size_t)DD * DD * 2);
  short* WtE    = (short*)alloc((size_t)DD * DD * 2);
  (void)ws_size; (void)n_in; (void)out_size;

  int nsb = (N + 255) / 256;

  hipMemsetAsync(deg, 0, (size_t)N * 4, stream);
  k_prewt5<<<5, 256, 0, stream>>>(WA, WB, WC, WD, WE, WtA, WtB, WtC, WtD, WtE);
  k_hist<<<(E + 255) / 256, 256, 0, stream>>>(dstI, deg, E);
  k_scan1<<<nsb, 256, 0, stream>>>(deg, off, totals, N);
  k_scan2<<<1, 256, 0, stream>>>(totals, boff, nsb);
  k_scan3<<<nsb, 256, 0, stream>>>(off, boff, cursor, N);
  k_fill<<<(E + 255) / 256, 256, 0, stream>>>(dstI, srcI, cursor, list, srcS, E);

  k_nodegemm<<<(N + 63) / 64, 256, 0, stream>>>(x, WtA, bA, WtB, bB, WtD, bD, WtE, bE,
                                                Axh, Bxh, Dxh, Exh, N);
  k_edge<<<ntilesE, 256, 0, stream>>>(e, WtC, bC, srcI, dstI, Dxh, Exh, eij, pE, E);
  k_reduce<<<128, 256, 0, stream>>>(pE, ntilesE, 1.0f / (float)E, ge, be, statsE);

  k_gather<<<NB_G, 256, 0, stream>>>(off, deg, list, srcS, eij, Bxh, Axh, statsE,
                                     outx, oute, pX, N);
  k_reduce<<<128, 256, 0, stream>>>(pX, NB_G, 1.0f / (float)N, gx, bx, statsX);
  k_xfinal<<<(int)(((size_t)N * DD / 4 + 255) / 256), 256, 0, stream>>>(outx, statsX, (size_t)N * DD / 4);
}

// Round 7
// 599.396 us; speedup vs baseline: 1.3890x; 1.1594x over previous
//
#include <hip/hip_runtime.h>
#include <stdint.h>

#define DD 128
#define NB_G 2048   // k_gather blocks
#define GE   2048   // k_edge persistent blocks

using f32x4  = __attribute__((ext_vector_type(4))) float;
using bf16x8 = __attribute__((ext_vector_type(8))) short;

__device__ __forceinline__ float bf2f(short u) {
  union { unsigned int i; float f; } c;
  c.i = ((unsigned int)(unsigned short)u) << 16;
  return c.f;
}
__device__ __forceinline__ short f2bf(float f) {
  union { float f; unsigned int i; } c;
  c.f = f;
  unsigned int u = c.i;
  u += 0x7fffu + ((u >> 16) & 1u);
  return (short)(u >> 16);
}

// ---------------- CSR build ----------------
__global__ __launch_bounds__(256) void k_hist(const int* __restrict__ dst, int* __restrict__ deg, int E) {
  int e = blockIdx.x * 256 + threadIdx.x;
  if (e < E) atomicAdd(&deg[dst[e]], 1);
}

__global__ __launch_bounds__(256) void k_scan1(const int* __restrict__ deg, int* __restrict__ off,
                                               int* __restrict__ totals, int n) {
  __shared__ int sm[256];
  int t = threadIdx.x;
  int i = blockIdx.x * 256 + t;
  int v = (i < n) ? deg[i] : 0;
  sm[t] = v;
  __syncthreads();
  int acc = v;
  #pragma unroll
  for (int d = 1; d < 256; d <<= 1) {
    int add = (t >= d) ? sm[t - d] : 0;
    __syncthreads();
    acc += add;
    sm[t] = acc;
    __syncthreads();
  }
  if (i < n) off[i] = acc - v;          // exclusive
  if (t == 255) totals[blockIdx.x] = acc;
}

__global__ __launch_bounds__(256) void k_scan2(const int* __restrict__ totals, int* __restrict__ boff, int nb) {
  __shared__ int sm[256];
  int t = threadIdx.x;
  int v = (t < nb) ? totals[t] : 0;
  sm[t] = v;
  __syncthreads();
  int acc = v;
  #pragma unroll
  for (int d = 1; d < 256; d <<= 1) {
    int add = (t >= d) ? sm[t - d] : 0;
    __syncthreads();
    acc += add;
    sm[t] = acc;
    __syncthreads();
  }
  boff[t] = acc - v;
}

__global__ __launch_bounds__(256) void k_scan3(int* __restrict__ off, const int* __restrict__ boff,
                                               int* __restrict__ cursor, int n) {
  int i = blockIdx.x * 256 + threadIdx.x;
  if (i < n) {
    int o = off[i] + boff[blockIdx.x];
    off[i] = o;
    cursor[i] = o;
  }
}

// fill CSR: list (slot->edge), srcS (slot->src), posOf (edge->slot)
__global__ __launch_bounds__(256) void k_fill(const int* __restrict__ dst, const int* __restrict__ src,
                                              int* __restrict__ cursor, int* __restrict__ list,
                                              int* __restrict__ srcS, int* __restrict__ posOf, int E) {
  int e = blockIdx.x * 256 + threadIdx.x;
  if (e < E) {
    int p = atomicAdd(&cursor[dst[e]], 1);
    list[p] = e;
    srcS[p] = src[e];
    posOf[e] = p;
  }
}

// ---------------- one-time weight convert+transpose: Wt[c][k] = bf16(W[k][c]) ----------------
__global__ __launch_bounds__(256) void k_prewt5(
    const float* __restrict__ WA, const float* __restrict__ WB, const float* __restrict__ WC,
    const float* __restrict__ WD, const float* __restrict__ WE,
    short* __restrict__ WtA, short* __restrict__ WtB, short* __restrict__ WtC,
    short* __restrict__ WtD, short* __restrict__ WtE) {
  const float* Ws[5] = {WA, WB, WC, WD, WE};
  short* Os[5] = {WtA, WtB, WtC, WtD, WtE};
  const float* W = Ws[blockIdx.x];
  short* O = Os[blockIdx.x];
  int t = threadIdx.x, c = t & 127, h = t >> 7;
  for (int p = 0; p < 8; ++p) {
    int k0 = (h * 8 + p) * 8;
    bf16x8 v;
    #pragma unroll
    for (int j = 0; j < 8; ++j) v[j] = f2bf(W[(size_t)(k0 + j) * DD + c]);
    *(bf16x8*)&O[(size_t)c * DD + k0] = v;
  }
}

// ---------------- node-side GEMMs (swapped MFMA; register-local epilogue) ----------
__global__ __launch_bounds__(256) void k_nodegemm(
    const float* __restrict__ x,
    const short* __restrict__ WtA, const float* __restrict__ bA,
    const short* __restrict__ WtB, const float* __restrict__ bB,
    const short* __restrict__ WtD, const float* __restrict__ bD,
    const short* __restrict__ WtE, const float* __restrict__ bE,
    short* __restrict__ Axh, short* __restrict__ Bxh,
    short* __restrict__ Dxh, short* __restrict__ Exh, int n) {
  int t = threadIdx.x;
  int w = t >> 6, l = t & 63, lg = l >> 4, lc = l & 15;
  int m0 = blockIdx.x * 64;
  int row = m0 + w * 16 + lc;
  bool valid = row < n;
  int rowc = valid ? row : n - 1;

  const float* xr = x + (size_t)rowc * DD;
  bf16x8 af[4];
  #pragma unroll
  for (int kk = 0; kk < 4; ++kk) {
    float4 a0 = *(const float4*)&xr[kk * 32 + lg * 8];
    float4 a1 = *(const float4*)&xr[kk * 32 + lg * 8 + 4];
    af[kk][0] = f2bf(a0.x); af[kk][1] = f2bf(a0.y); af[kk][2] = f2bf(a0.z); af[kk][3] = f2bf(a0.w);
    af[kk][4] = f2bf(a1.x); af[kk][5] = f2bf(a1.y); af[kk][6] = f2bf(a1.z); af[kk][7] = f2bf(a1.w);
  }

  const short* Wt[4] = {WtA, WtB, WtD, WtE};
  const float* bs[4] = {bA, bB, bD, bE};
  short* Os[4] = {Axh, Bxh, Dxh, Exh};

  #pragma unroll
  for (int mi = 0; mi < 4; ++mi) {
    const short* Wm = Wt[mi];
    f32x4 acc[8] = {};
    #pragma unroll
    for (int kk = 0; kk < 4; ++kk) {
      #pragma unroll
      for (int tt = 0; tt < 8; ++tt) {
        bf16x8 bfv = *(const bf16x8*)&Wm[(size_t)(tt * 16 + lc) * DD + kk * 32 + lg * 8];
        acc[tt] = __builtin_amdgcn_mfma_f32_16x16x32_bf16(bfv, af[kk], acc[tt], 0, 0, 0);
      }
    }
    if (valid) {
      short* O = Os[mi];
      #pragma unroll
      for (int tt = 0; tt < 8; ++tt) {
        int f0 = tt * 16 + lg * 4;
        float4 bc = *(const float4*)&bs[mi][f0];
        short4 o;
        o.x = f2bf(acc[tt][0] + bc.x);
        o.y = f2bf(acc[tt][1] + bc.y);
        o.z = f2bf(acc[tt][2] + bc.z);
        o.w = f2bf(acc[tt][3] + bc.w);
        *(short4*)&O[(size_t)row * DD + f0] = o;
      }
    }
  }
}

// ---------------- edge kernel: pipelined grid-stride; Ce GEMM + Dx[dst]+Ex[src]+bC -> eijS
// (CSR order via posOf scatter); fused e-stat partials. Next tile's e-rows + indices
// prefetched into registers; Dx/Ex gathers issued at loop top -> latency hides under MFMA.
__global__ __launch_bounds__(256) void k_edge(
    const float* __restrict__ e, const short* __restrict__ WtC, const float* __restrict__ bC,
    const int* __restrict__ srcI, const int* __restrict__ dstI, const int* __restrict__ posOf,
    const short* __restrict__ Dxh, const short* __restrict__ Exh,
    short* __restrict__ eijS, float* __restrict__ pE, int Etot, int ntiles) {
  __shared__ __align__(16) short es[4][16][136];   // per-wave private restage
  __shared__ float sE[4][128], qE[4][128];
  int t = threadIdx.x;
  int w = t >> 6, l = t & 63, lg = l >> 4, lc = l & 15;

  float bCv[8];
  #pragma unroll
  for (int tt = 0; tt < 8; ++tt) bCv[tt] = bC[tt * 16 + lc];

  float se[8] = {}, qe[8] = {};

  const int stride = gridDim.x;
  int tile = blockIdx.x;

  float4 e32[8];
  int dnN[4], snN[4], posN[4];

  // prefetch first tile
  {
    size_t m0 = (size_t)tile * 64;
    size_t row = m0 + w * 16 + lc;
    if (row >= (size_t)Etot) row = Etot - 1;
    const float* er = e + row * DD;
    #pragma unroll
    for (int kk = 0; kk < 4; ++kk) {
      e32[kk * 2]     = *(const float4*)&er[kk * 32 + lg * 8];
      e32[kk * 2 + 1] = *(const float4*)&er[kk * 32 + lg * 8 + 4];
    }
    #pragma unroll
    for (int z = 0; z < 4; ++z) {
      size_t erow = m0 + w * 16 + z * 4 + lg;
      if (erow >= (size_t)Etot) erow = Etot - 1;
      dnN[z] = dstI[erow]; snN[z] = srcI[erow]; posN[z] = posOf[erow];
    }
  }

  for (; tile < ntiles; tile += stride) {
    int dn[4], sn[4], pos[4];
    #pragma unroll
    for (int z = 0; z < 4; ++z) { dn[z] = dnN[z]; sn[z] = snN[z]; pos[z] = posN[z]; }

    // issue Dx/Ex row gathers for CURRENT tile (consumed in epilogue; overlap MFMA)
    bf16x8 dv[4], sv[4];
    #pragma unroll
    for (int z = 0; z < 4; ++z) {
      dv[z] = *(const bf16x8*)&Dxh[(size_t)dn[z] * DD + lc * 8];
      sv[z] = *(const bf16x8*)&Exh[(size_t)sn[z] * DD + lc * 8];
    }

    // convert current e-rows (loaded last iteration) to bf16 fragments
    bf16x8 af[4];
    #pragma unroll
    for (int kk = 0; kk < 4; ++kk) {
      float4 a0 = e32[kk * 2], a1 = e32[kk * 2 + 1];
      af[kk][0] = f2bf(a0.x); af[kk][1] = f2bf(a0.y); af[kk][2] = f2bf(a0.z); af[kk][3] = f2bf(a0.w);
      af[kk][4] = f2bf(a1.x); af[kk][5] = f2bf(a1.y); af[kk][6] = f2bf(a1.z); af[kk][7] = f2bf(a1.w);
    }

    // prefetch NEXT tile (e-rows f32 + epilogue indices): hides HBM under MFMA+epilogue
    int nt = tile + stride;
    if (nt < ntiles) {
      size_t m0n = (size_t)nt * 64;
      size_t row = m0n + w * 16 + lc;
      if (row >= (size_t)Etot) row = Etot - 1;
      const float* er = e + row * DD;
      #pragma unroll
      for (int kk = 0; kk < 4; ++kk) {
        e32[kk * 2]     = *(const float4*)&er[kk * 32 + lg * 8];
        e32[kk * 2 + 1] = *(const float4*)&er[kk * 32 + lg * 8 + 4];
      }
      #pragma unroll
      for (int z = 0; z < 4; ++z) {
        size_t erow = m0n + w * 16 + z * 4 + lg;
        if (erow >= (size_t)Etot) erow = Etot - 1;
        dnN[z] = dstI[erow]; snN[z] = srcI[erow]; posN[z] = posOf[erow];
      }
    }

    // GEMM (B-fragments from L2-hot WtC)
    f32x4 acc[8] = {};
    #pragma unroll
    for (int kk = 0; kk < 4; ++kk) {
      #pragma unroll
      for (int tt = 0; tt < 8; ++tt) {
        bf16x8 bfv = *(const bf16x8*)&WtC[(size_t)(tt * 16 + lc) * DD + kk * 32 + lg * 8];
        acc[tt] = __builtin_amdgcn_mfma_f32_16x16x32_bf16(af[kk], bfv, acc[tt], 0, 0, 0);
      }
    }

    // restage Ce+bC so epilogue rows are lane-contiguous
    #pragma unroll
    for (int tt = 0; tt < 8; ++tt) {
      int col = tt * 16 + lc;
      #pragma unroll
      for (int j = 0; j < 4; ++j)
        es[w][lg * 4 + j][col] = f2bf(acc[tt][j] + bCv[tt]);
    }
    asm volatile("s_waitcnt lgkmcnt(0)" ::: "memory");
    __builtin_amdgcn_sched_barrier(0);

    size_t m0 = (size_t)tile * 64;
    #pragma unroll
    for (int z = 0; z < 4; ++z) {
      size_t erow = m0 + w * 16 + z * 4 + lg;
      if (erow < (size_t)Etot) {
        int r = z * 4 + lg;
        bf16x8 cv = *(const bf16x8*)&es[w][r][lc * 8];
        bf16x8 o;
        #pragma unroll
        for (int j = 0; j < 8; ++j) {
          float v = bf2f(cv[j]) + bf2f(dv[z][j]) + bf2f(sv[z][j]);
          se[j] += v; qe[j] += v * v;
          o[j] = f2bf(v);
        }
        *(bf16x8*)&eijS[(size_t)pos[z] * DD + lc * 8] = o;
      }
    }
    __builtin_amdgcn_sched_barrier(0);
  }

  // block-level stat partials (once per block)
  #pragma unroll
  for (int j = 0; j < 8; ++j) {
    se[j] += __shfl_xor(se[j], 16); se[j] += __shfl_xor(se[j], 32);
    qe[j] += __shfl_xor(qe[j], 16); qe[j] += __shfl_xor(qe[j], 32);
  }
  if (lg == 0) {
    #pragma unroll
    for (int j = 0; j < 8; ++j) { sE[w][lc * 8 + j] = se[j]; qE[w][lc * 8 + j] = qe[j]; }
  }
  __syncthreads();
  if (t < 128) {
    float a = sE[0][t] + sE[1][t] + sE[2][t] + sE[3][t];
    float b = qE[0][t] + qE[1][t] + qE[2][t] + qE[3][t];
    pE[(size_t)blockIdx.x * 256 + t] = a;
    pE[(size_t)blockIdx.x * 256 + 128 + t] = b;
  }
}

// ---------------- gather: streaming CSR reads + x_pre + fused e_out write ----------------
__global__ __launch_bounds__(256) void k_gather(
    const int* __restrict__ off, const int* __restrict__ deg, const int* __restrict__ list,
    const int* __restrict__ srcS, const short* __restrict__ eijS, const short* __restrict__ Bxh,
    const short* __restrict__ Axh, const float* __restrict__ stE,
    float* __restrict__ outx, float* __restrict__ oute,
    float* __restrict__ pX, int n) {
  int t = threadIdx.x;
  int w = t >> 6, l = t & 63;
  int qw = l >> 4, fi = l & 15;
  int waveId = blockIdx.x * 4 + w;
  const int nwaves = NB_G * 4;

  float su[8], hu[8];
  {
    float4 s0 = *(const float4*)&stE[fi * 8], s1 = *(const float4*)&stE[fi * 8 + 4];
    float4 h0 = *(const float4*)&stE[128 + fi * 8], h1 = *(const float4*)&stE[128 + fi * 8 + 4];
    su[0] = s0.x; su[1] = s0.y; su[2] = s0.z; su[3] = s0.w;
    su[4] = s1.x; su[5] = s1.y; su[6] = s1.z; su[7] = s1.w;
    hu[0] = h0.x; hu[1] = h0.y; hu[2] = h0.z; hu[3] = h0.w;
    hu[4] = h1.x; hu[5] = h1.y; hu[6] = h1.z; hu[7] = h1.w;
  }

  float sx[4] = {}, qx[4] = {};

  for (int node = waveId; node < n; node += nwaves) {
    int start = off[node], dg = deg[node];
    float num[8] = {}, den[8] = {};
    int k = qw;
    for (; k + 4 < dg; k += 8) {
      int p0 = start + k, p1 = start + k + 4;
      int id0 = list[p0], id1 = list[p1];
      int s0 = srcS[p0], s1 = srcS[p1];
      bf16x8 e0 = *(const bf16x8*)&eijS[(size_t)p0 * DD + fi * 8];   // streaming
      bf16x8 e1 = *(const bf16x8*)&eijS[(size_t)p1 * DD + fi * 8];
      bf16x8 b0 = *(const bf16x8*)&Bxh[(size_t)s0 * DD + fi * 8];
      bf16x8 b1 = *(const bf16x8*)&Bxh[(size_t)s1 * DD + fi * 8];
      float4 oa, ob, oc, od;
      float v0a[8], v1a[8];
      #pragma unroll
      for (int j = 0; j < 8; ++j) {
        float v0 = bf2f(e0[j]), v1 = bf2f(e1[j]);
        v0a[j] = fmaxf(0.f, v0 * su[j] + hu[j]);
        v1a[j] = fmaxf(0.f, v1 * su[j] + hu[j]);
        float g0 = 1.f / (1.f + __expf(-v0)), g1 = 1.f / (1.f + __expf(-v1));
        num[j] += g0 * bf2f(b0[j]) + g1 * bf2f(b1[j]);
        den[j] += g0 + g1;
      }
      oa.x = v0a[0]; oa.y = v0a[1]; oa.z = v0a[2]; oa.w = v0a[3];
      ob.x = v0a[4]; ob.y = v0a[5]; ob.z = v0a[6]; ob.w = v0a[7];
      oc.x = v1a[0]; oc.y = v1a[1]; oc.z = v1a[2]; oc.w = v1a[3];
      od.x = v1a[4]; od.y = v1a[5]; od.z = v1a[6]; od.w = v1a[7];
      *(float4*)&oute[(size_t)id0 * DD + fi * 8] = oa;
      *(float4*)&oute[(size_t)id0 * DD + fi * 8 + 4] = ob;
      *(float4*)&oute[(size_t)id1 * DD + fi * 8] = oc;
      *(float4*)&oute[(size_t)id1 * DD + fi * 8 + 4] = od;
    }
    for (; k < dg; k += 4) {
      int p0 = start + k;
      int id0 = list[p0];
      int s0 = srcS[p0];
      bf16x8 e0 = *(const bf16x8*)&eijS[(size_t)p0 * DD + fi * 8];
      bf16x8 b0 = *(const bf16x8*)&Bxh[(size_t)s0 * DD + fi * 8];
      float4 oa, ob;
      float v0a[8];
      #pragma unroll
      for (int j = 0; j < 8; ++j) {
        float v0 = bf2f(e0[j]);
        v0a[j] = fmaxf(0.f, v0 * su[j] + hu[j]);
        float g0 = 1.f / (1.f + __expf(-v0));
        num[j] += g0 * bf2f(b0[j]);
        den[j] += g0;
      }
      oa.x = v0a[0]; oa.y = v0a[1]; oa.z = v0a[2]; oa.w = v0a[3];
      ob.x = v0a[4]; ob.y = v0a[5]; ob.z = v0a[6]; ob.w = v0a[7];
      *(float4*)&oute[(size_t)id0 * DD + fi * 8] = oa;
      *(float4*)&oute[(size_t)id0 * DD + fi * 8 + 4] = ob;
    }
    #pragma unroll
    for (int j = 0; j < 8; ++j) {
      num[j] += __shfl_xor(num[j], 16); num[j] += __shfl_xor(num[j], 32);
      den[j] += __shfl_xor(den[j], 16); den[j] += __shfl_xor(den[j], 32);
    }
    if (qw < 2) {
      int c0 = fi * 8 + qw * 4;
      short4 ax = *(const short4*)&Axh[(size_t)node * DD + c0];
      short axa[4] = {ax.x, ax.y, ax.z, ax.w};
      float4 o;
      float vv[4];
      #pragma unroll
      for (int j = 0; j < 4; ++j) {
        int jj = qw * 4 + j;
        float aggr = num[jj] / (den[jj] + 1e-6f);
        float xp = bf2f(axa[j]) + aggr;
        vv[j] = xp;
        sx[j] += xp; qx[j] += xp * xp;
      }
      o.x = vv[0]; o.y = vv[1]; o.z = vv[2]; o.w = vv[3];
      *(float4*)&outx[(size_t)node * DD + c0] = o;
    }
  }

  __shared__ float lsX[4][128], lqX[4][128];
  if (qw < 2) {
    #pragma unroll
    for (int j = 0; j < 4; ++j) { lsX[w][fi * 8 + qw * 4 + j] = sx[j]; lqX[w][fi * 8 + qw * 4 + j] = qx[j]; }
  }
  __syncthreads();
  if (t < 128) {
    float a = lsX[0][t] + lsX[1][t] + lsX[2][t] + lsX[3][t];
    float b = lqX[0][t] + lqX[1][t] + lqX[2][t] + lqX[3][t];
    pX[(size_t)blockIdx.x * 256 + t] = a;
    pX[(size_t)blockIdx.x * 256 + 128 + t] = b;
  }
}

// reduce partials -> folded BN affine: stats[c]=scale, stats[128+c]=shift
__global__ __launch_bounds__(256) void k_reduce(const float* __restrict__ part, int nblk, float invcnt,
                                                const float* __restrict__ gamma, const float* __restrict__ beta,
                                                float* __restrict__ stats) {
  int c = blockIdx.x, t = threadIdx.x;
  float a = 0.f, b = 0.f;
  for (int k = t; k < nblk; k += 256) {
    a += part[(size_t)k * 256 + c];
    b += part[(size_t)k * 256 + 128 + c];
  }
  #pragma unroll
  for (int o = 32; o > 0; o >>= 1) { a += __shfl_down(a, o); b += __shfl_down(b, o); }
  __shared__ float ra[4], rb[4];
  int l = t & 63, w = t >> 6;
  if (l == 0) { ra[w] = a; rb[w] = b; }
  __syncthreads();
  if (t == 0) {
    a = ra[0] + ra[1] + ra[2] + ra[3];
    b = rb[0] + rb[1] + rb[2] + rb[3];
    float mean = a * invcnt;
    float var = b * invcnt - mean * mean;   // biased variance
    float istd = rsqrtf(var + 1e-5f);
    float scale = gamma[c] * istd;
    stats[c] = scale;
    stats[128 + c] = beta[c] - mean * scale;
  }
}

// ---------------- finalize x ----------------
__global__ __launch_bounds__(256) void k_xfinal(float* __restrict__ v, const float* __restrict__ st, size_t n4) {
  size_t i = (size_t)blockIdx.x * 256 + threadIdx.x;
  if (i >= n4) return;
  float4 d = *(const float4*)&v[i * 4];
  int f0 = (int)((i * 4) & 127);
  d.x = fmaxf(0.f, d.x * st[f0 + 0] + st[128 + f0 + 0]);
  d.y = fmaxf(0.f, d.y * st[f0 + 1] + st[128 + f0 + 1]);
  d.z = fmaxf(0.f, d.z * st[f0 + 2] + st[128 + f0 + 2]);
  d.w = fmaxf(0.f, d.w * st[f0 + 3] + st[128 + f0 + 3]);
  *(float4*)&v[i * 4] = d;
}

extern "C" void kernel_launch(void* const* d_in, const int* in_sizes, int n_in,
                              void* d_out, int out_size, void* d_ws, size_t ws_size,
                              hipStream_t stream) {
  const float* x  = (const float*)d_in[0];
  const float* e  = (const float*)d_in[1];
  const int*   ei = (const int*)d_in[2];
  const float* WA = (const float*)d_in[3];  const float* bA = (const float*)d_in[4];
  const float* WB = (const float*)d_in[5];  const float* bB = (const float*)d_in[6];
  const float* WC = (const float*)d_in[7];  const float* bC = (const float*)d_in[8];
  const float* WD = (const float*)d_in[9];  const float* bD = (const float*)d_in[10];
  const float* WE = (const float*)d_in[11]; const float* bE = (const float*)d_in[12];
  const float* gx = (const float*)d_in[13]; const float* bx = (const float*)d_in[14];
  const float* ge = (const float*)d_in[15]; const float* be = (const float*)d_in[16];

  int N = in_sizes[0] / DD;
  int E = in_sizes[2] / 2;
  const int* srcI = ei;       // edge_index[0]
  const int* dstI = ei + E;   // edge_index[1]

  float* outx = (float*)d_out;
  float* oute = (float*)d_out + (size_t)N * DD;

  int ntilesE = (E + 63) / 64;

  char* wp = (char*)d_ws;
  auto alloc = [&](size_t sz) { char* p = wp; wp += (sz + 255) & ~(size_t)255; return p; };
  short* Axh    = (short*)alloc((size_t)N * DD * 2);
  short* Bxh    = (short*)alloc((size_t)N * DD * 2);
  short* Dxh    = (short*)alloc((size_t)N * DD * 2);
  short* Exh    = (short*)alloc((size_t)N * DD * 2);
  short* eijS   = (short*)alloc((size_t)E * DD * 2);
  int*   deg    = (int*)alloc((size_t)N * 4);
  int*   off    = (int*)alloc((size_t)N * 4);
  int*   cursor = (int*)alloc((size_t)N * 4);
  int*   totals = (int*)alloc(1024);
  int*   boff   = (int*)alloc(1024);
  int*   list   = (int*)alloc((size_t)E * 4);
  int*   srcS   = (int*)alloc((size_t)E * 4);
  int*   posOf  = (int*)alloc((size_t)E * 4);
  float* pE     = (float*)alloc((size_t)GE * 256 * 4);
  float* pX     = (float*)alloc((size_t)NB_G * 256 * 4);
  float* statsE = (float*)alloc(1024);
  float* statsX = (float*)alloc(1024);
  short* WtA    = (short*)alloc((size_t)DD * DD * 2);
  short* WtB    = (short*)alloc((size_t)DD * DD * 2);
  short* WtC    = (short*)alloc((size_t)DD * DD * 2);
  short* WtD    = (short*)alloc((size_t)DD * DD * 2);
  short* WtE    = (short*)alloc((size_t)DD * DD * 2);
  (void)ws_size; (void)n_in; (void)out_size;

  int nsb = (N + 255) / 256;

  hipMemsetAsync(deg, 0, (size_t)N * 4, stream);
  k_prewt5<<<5, 256, 0, stream>>>(WA, WB, WC, WD, WE, WtA, WtB, WtC, WtD, WtE);
  k_hist<<<(E + 255) / 256, 256, 0, stream>>>(dstI, deg, E);
  k_scan1<<<nsb, 256, 0, stream>>>(deg, off, totals, N);
  k_scan2<<<1, 256, 0, stream>>>(totals, boff, nsb);
  k_scan3<<<nsb, 256, 0, stream>>>(off, boff, cursor, N);
  k_fill<<<(E + 255) / 256, 256, 0, stream>>>(dstI, srcI, cursor, list, srcS, posOf, E);

  k_nodegemm<<<(N + 63) / 64, 256, 0, stream>>>(x, WtA, bA, WtB, bB, WtD, bD, WtE, bE,
                                                Axh, Bxh, Dxh, Exh, N);
  k_edge<<<GE, 256, 0, stream>>>(e, WtC, bC, srcI, dstI, posOf, Dxh, Exh, eijS, pE, E, ntilesE);
  k_reduce<<<128, 256, 0, stream>>>(pE, GE, 1.0f / (float)E, ge, be, statsE);

  k_gather<<<NB_G, 256, 0, stream>>>(off, deg, list, srcS, eijS, Bxh, Axh, statsE,
                                     outx, oute, pX, N);
  k_reduce<<<128, 256, 0, stream>>>(pX, NB_G, 1.0f / (float)N, gx, bx, statsX);
  k_xfinal<<<(int)(((size_t)N * DD / 4 + 255) / 256), 256, 0, stream>>>(outx, statsX, (size_t)N * DD / 4);
}

// Round 8
// 599.369 us; speedup vs baseline: 1.3890x; 1.0000x over previous
//
#include <hip/hip_runtime.h>
#include <stdint.h>

#define DD 128
#define NB_G 2048   // k_gather blocks
#define GE   2048   // k_edge persistent blocks

using f32x4  = __attribute__((ext_vector_type(4))) float;
using bf16x8 = __attribute__((ext_vector_type(8))) short;

__device__ __forceinline__ float bf2f(short u) {
  union { unsigned int i; float f; } c;
  c.i = ((unsigned int)(unsigned short)u) << 16;
  return c.f;
}
__device__ __forceinline__ short f2bf(float f) {
  union { float f; unsigned int i; } c;
  c.f = f;
  unsigned int u = c.i;
  u += 0x7fffu + ((u >> 16) & 1u);
  return (short)(u >> 16);
}

// ---------------- zero deg (replaces graph-captured hipMemsetAsync: 250us anomaly, R7) -------
__global__ __launch_bounds__(256) void k_zero(int* __restrict__ p, int n) {
  int i = blockIdx.x * 256 + threadIdx.x;
  if (i < n) p[i] = 0;
}

// ---------------- CSR build ----------------
__global__ __launch_bounds__(256) void k_hist(const int* __restrict__ dst, int* __restrict__ deg, int E) {
  int e = blockIdx.x * 256 + threadIdx.x;
  if (e < E) atomicAdd(&deg[dst[e]], 1);
}

__global__ __launch_bounds__(256) void k_scan1(const int* __restrict__ deg, int* __restrict__ off,
                                               int* __restrict__ totals, int n) {
  __shared__ int sm[256];
  int t = threadIdx.x;
  int i = blockIdx.x * 256 + t;
  int v = (i < n) ? deg[i] : 0;
  sm[t] = v;
  __syncthreads();
  int acc = v;
  #pragma unroll
  for (int d = 1; d < 256; d <<= 1) {
    int add = (t >= d) ? sm[t - d] : 0;
    __syncthreads();
    acc += add;
    sm[t] = acc;
    __syncthreads();
  }
  if (i < n) off[i] = acc - v;          // exclusive
  if (t == 255) totals[blockIdx.x] = acc;
}

__global__ __launch_bounds__(256) void k_scan2(const int* __restrict__ totals, int* __restrict__ boff, int nb) {
  __shared__ int sm[256];
  int t = threadIdx.x;
  int v = (t < nb) ? totals[t] : 0;
  sm[t] = v;
  __syncthreads();
  int acc = v;
  #pragma unroll
  for (int d = 1; d < 256; d <<= 1) {
    int add = (t >= d) ? sm[t - d] : 0;
    __syncthreads();
    acc += add;
    sm[t] = acc;
    __syncthreads();
  }
  boff[t] = acc - v;
}

__global__ __launch_bounds__(256) void k_scan3(int* __restrict__ off, const int* __restrict__ boff,
                                               int* __restrict__ cursor, int n) {
  int i = blockIdx.x * 256 + threadIdx.x;
  if (i < n) {
    int o = off[i] + boff[blockIdx.x];
    off[i] = o;
    cursor[i] = o;
  }
}

// fill CSR: list (slot->edge), srcS (slot->src), posOf (edge->slot)
__global__ __launch_bounds__(256) void k_fill(const int* __restrict__ dst, const int* __restrict__ src,
                                              int* __restrict__ cursor, int* __restrict__ list,
                                              int* __restrict__ srcS, int* __restrict__ posOf, int E) {
  int e = blockIdx.x * 256 + threadIdx.x;
  if (e < E) {
    int p = atomicAdd(&cursor[dst[e]], 1);
    list[p] = e;
    srcS[p] = src[e];
    posOf[e] = p;
  }
}

// ---------------- one-time weight convert+transpose: Wt[c][k] = bf16(W[k][c]) ----------------
__global__ __launch_bounds__(256) void k_prewt5(
    const float* __restrict__ WA, const float* __restrict__ WB, const float* __restrict__ WC,
    const float* __restrict__ WD, const float* __restrict__ WE,
    short* __restrict__ WtA, short* __restrict__ WtB, short* __restrict__ WtC,
    short* __restrict__ WtD, short* __restrict__ WtE) {
  const float* Ws[5] = {WA, WB, WC, WD, WE};
  short* Os[5] = {WtA, WtB, WtC, WtD, WtE};
  const float* W = Ws[blockIdx.x];
  short* O = Os[blockIdx.x];
  int t = threadIdx.x, c = t & 127, h = t >> 7;
  for (int p = 0; p < 8; ++p) {
    int k0 = (h * 8 + p) * 8;
    bf16x8 v;
    #pragma unroll
    for (int j = 0; j < 8; ++j) v[j] = f2bf(W[(size_t)(k0 + j) * DD + c]);
    *(bf16x8*)&O[(size_t)c * DD + k0] = v;
  }
}

// ---------------- node-side GEMMs (swapped MFMA; register-local epilogue) ----------
__global__ __launch_bounds__(256) void k_nodegemm(
    const float* __restrict__ x,
    const short* __restrict__ WtA, const float* __restrict__ bA,
    const short* __restrict__ WtB, const float* __restrict__ bB,
    const short* __restrict__ WtD, const float* __restrict__ bD,
    const short* __restrict__ WtE, const float* __restrict__ bE,
    short* __restrict__ Axh, short* __restrict__ Bxh,
    short* __restrict__ Dxh, short* __restrict__ Exh, int n) {
  int t = threadIdx.x;
  int w = t >> 6, l = t & 63, lg = l >> 4, lc = l & 15;
  int m0 = blockIdx.x * 64;
  int row = m0 + w * 16 + lc;
  bool valid = row < n;
  int rowc = valid ? row : n - 1;

  const float* xr = x + (size_t)rowc * DD;
  bf16x8 af[4];
  #pragma unroll
  for (int kk = 0; kk < 4; ++kk) {
    float4 a0 = *(const float4*)&xr[kk * 32 + lg * 8];
    float4 a1 = *(const float4*)&xr[kk * 32 + lg * 8 + 4];
    af[kk][0] = f2bf(a0.x); af[kk][1] = f2bf(a0.y); af[kk][2] = f2bf(a0.z); af[kk][3] = f2bf(a0.w);
    af[kk][4] = f2bf(a1.x); af[kk][5] = f2bf(a1.y); af[kk][6] = f2bf(a1.z); af[kk][7] = f2bf(a1.w);
  }

  const short* Wt[4] = {WtA, WtB, WtD, WtE};
  const float* bs[4] = {bA, bB, bD, bE};
  short* Os[4] = {Axh, Bxh, Dxh, Exh};

  #pragma unroll
  for (int mi = 0; mi < 4; ++mi) {
    const short* Wm = Wt[mi];
    f32x4 acc[8] = {};
    #pragma unroll
    for (int kk = 0; kk < 4; ++kk) {
      #pragma unroll
      for (int tt = 0; tt < 8; ++tt) {
        bf16x8 bfv = *(const bf16x8*)&Wm[(size_t)(tt * 16 + lc) * DD + kk * 32 + lg * 8];
        acc[tt] = __builtin_amdgcn_mfma_f32_16x16x32_bf16(bfv, af[kk], acc[tt], 0, 0, 0);
      }
    }
    if (valid) {
      short* O = Os[mi];
      #pragma unroll
      for (int tt = 0; tt < 8; ++tt) {
        int f0 = tt * 16 + lg * 4;
        float4 bc = *(const float4*)&bs[mi][f0];
        short4 o;
        o.x = f2bf(acc[tt][0] + bc.x);
        o.y = f2bf(acc[tt][1] + bc.y);
        o.z = f2bf(acc[tt][2] + bc.z);
        o.w = f2bf(acc[tt][3] + bc.w);
        *(short4*)&O[(size_t)row * DD + f0] = o;
      }
    }
  }
}

// ---------------- edge kernel: pipelined grid-stride; Ce GEMM + Dx[dst]+Ex[src]+bC -> eijS
// (CSR order via posOf scatter); fused e-stat partials.
__global__ __launch_bounds__(256) void k_edge(
    const float* __restrict__ e, const short* __restrict__ WtC, const float* __restrict__ bC,
    const int* __restrict__ srcI, const int* __restrict__ dstI, const int* __restrict__ posOf,
    const short* __restrict__ Dxh, const short* __restrict__ Exh,
    short* __restrict__ eijS, float* __restrict__ pE, int Etot, int ntiles) {
  __shared__ __align__(16) short es[4][16][136];   // per-wave private restage
  __shared__ float sE[4][128], qE[4][128];
  int t = threadIdx.x;
  int w = t >> 6, l = t & 63, lg = l >> 4, lc = l & 15;

  float bCv[8];
  #pragma unroll
  for (int tt = 0; tt < 8; ++tt) bCv[tt] = bC[tt * 16 + lc];

  float se[8] = {}, qe[8] = {};

  const int stride = gridDim.x;
  int tile = blockIdx.x;

  float4 e32[8];
  int dnN[4], snN[4], posN[4];

  // prefetch first tile
  {
    size_t m0 = (size_t)tile * 64;
    size_t row = m0 + w * 16 + lc;
    if (row >= (size_t)Etot) row = Etot - 1;
    const float* er = e + row * DD;
    #pragma unroll
    for (int kk = 0; kk < 4; ++kk) {
      e32[kk * 2]     = *(const float4*)&er[kk * 32 + lg * 8];
      e32[kk * 2 + 1] = *(const float4*)&er[kk * 32 + lg * 8 + 4];
    }
    #pragma unroll
    for (int z = 0; z < 4; ++z) {
      size_t erow = m0 + w * 16 + z * 4 + lg;
      if (erow >= (size_t)Etot) erow = Etot - 1;
      dnN[z] = dstI[erow]; snN[z] = srcI[erow]; posN[z] = posOf[erow];
    }
  }

  for (; tile < ntiles; tile += stride) {
    int dn[4], sn[4], pos[4];
    #pragma unroll
    for (int z = 0; z < 4; ++z) { dn[z] = dnN[z]; sn[z] = snN[z]; pos[z] = posN[z]; }

    // issue Dx/Ex row gathers for CURRENT tile (consumed in epilogue; overlap MFMA)
    bf16x8 dv[4], sv[4];
    #pragma unroll
    for (int z = 0; z < 4; ++z) {
      dv[z] = *(const bf16x8*)&Dxh[(size_t)dn[z] * DD + lc * 8];
      sv[z] = *(const bf16x8*)&Exh[(size_t)sn[z] * DD + lc * 8];
    }

    // convert current e-rows (loaded last iteration) to bf16 fragments
    bf16x8 af[4];
    #pragma unroll
    for (int kk = 0; kk < 4; ++kk) {
      float4 a0 = e32[kk * 2], a1 = e32[kk * 2 + 1];
      af[kk][0] = f2bf(a0.x); af[kk][1] = f2bf(a0.y); af[kk][2] = f2bf(a0.z); af[kk][3] = f2bf(a0.w);
      af[kk][4] = f2bf(a1.x); af[kk][5] = f2bf(a1.y); af[kk][6] = f2bf(a1.z); af[kk][7] = f2bf(a1.w);
    }

    // prefetch NEXT tile (e-rows f32 + epilogue indices)
    int nt = tile + stride;
    if (nt < ntiles) {
      size_t m0n = (size_t)nt * 64;
      size_t row = m0n + w * 16 + lc;
      if (row >= (size_t)Etot) row = Etot - 1;
      const float* er = e + row * DD;
      #pragma unroll
      for (int kk = 0; kk < 4; ++kk) {
        e32[kk * 2]     = *(const float4*)&er[kk * 32 + lg * 8];
        e32[kk * 2 + 1] = *(const float4*)&er[kk * 32 + lg * 8 + 4];
      }
      #pragma unroll
      for (int z = 0; z < 4; ++z) {
        size_t erow = m0n + w * 16 + z * 4 + lg;
        if (erow >= (size_t)Etot) erow = Etot - 1;
        dnN[z] = dstI[erow]; snN[z] = srcI[erow]; posN[z] = posOf[erow];
      }
    }

    // GEMM (B-fragments from L2-hot WtC)
    f32x4 acc[8] = {};
    #pragma unroll
    for (int kk = 0; kk < 4; ++kk) {
      #pragma unroll
      for (int tt = 0; tt < 8; ++tt) {
        bf16x8 bfv = *(const bf16x8*)&WtC[(size_t)(tt * 16 + lc) * DD + kk * 32 + lg * 8];
        acc[tt] = __builtin_amdgcn_mfma_f32_16x16x32_bf16(af[kk], bfv, acc[tt], 0, 0, 0);
      }
    }

    // restage Ce+bC so epilogue rows are lane-contiguous
    #pragma unroll
    for (int tt = 0; tt < 8; ++tt) {
      int col = tt * 16 + lc;
      #pragma unroll
      for (int j = 0; j < 4; ++j)
        es[w][lg * 4 + j][col] = f2bf(acc[tt][j] + bCv[tt]);
    }
    asm volatile("s_waitcnt lgkmcnt(0)" ::: "memory");
    __builtin_amdgcn_sched_barrier(0);

    size_t m0 = (size_t)tile * 64;
    #pragma unroll
    for (int z = 0; z < 4; ++z) {
      size_t erow = m0 + w * 16 + z * 4 + lg;
      if (erow < (size_t)Etot) {
        int r = z * 4 + lg;
        bf16x8 cv = *(const bf16x8*)&es[w][r][lc * 8];
        bf16x8 o;
        #pragma unroll
        for (int j = 0; j < 8; ++j) {
          float v = bf2f(cv[j]) + bf2f(dv[z][j]) + bf2f(sv[z][j]);
          se[j] += v; qe[j] += v * v;
          o[j] = f2bf(v);
        }
        *(bf16x8*)&eijS[(size_t)pos[z] * DD + lc * 8] = o;
      }
    }
    __builtin_amdgcn_sched_barrier(0);
  }

  // block-level stat partials (once per block)
  #pragma unroll
  for (int j = 0; j < 8; ++j) {
    se[j] += __shfl_xor(se[j], 16); se[j] += __shfl_xor(se[j], 32);
    qe[j] += __shfl_xor(qe[j], 16); qe[j] += __shfl_xor(qe[j], 32);
  }
  if (lg == 0) {
    #pragma unroll
    for (int j = 0; j < 8; ++j) { sE[w][lc * 8 + j] = se[j]; qE[w][lc * 8 + j] = qe[j]; }
  }
  __syncthreads();
  if (t < 128) {
    float a = sE[0][t] + sE[1][t] + sE[2][t] + sE[3][t];
    float b = qE[0][t] + qE[1][t] + qE[2][t] + qE[3][t];
    pE[(size_t)blockIdx.x * 256 + t] = a;
    pE[(size_t)blockIdx.x * 256 + 128 + t] = b;
  }
}

// ---------------- gather: streaming CSR reads + x_pre + fused e_out write ----------------
__global__ __launch_bounds__(256) void k_gather(
    const int* __restrict__ off, const int* __restrict__ deg, const int* __restrict__ list,
    const int* __restrict__ srcS, const short* __restrict__ eijS, const short* __restrict__ Bxh,
    const short* __restrict__ Axh, const float* __restrict__ stE,
    float* __restrict__ outx, float* __restrict__ oute,
    float* __restrict__ pX, int n) {
  int t = threadIdx.x;
  int w = t >> 6, l = t & 63;
  int qw = l >> 4, fi = l & 15;
  int waveId = blockIdx.x * 4 + w;
  const int nwaves = NB_G * 4;

  float su[8], hu[8];
  {
    float4 s0 = *(const float4*)&stE[fi * 8], s1 = *(const float4*)&stE[fi * 8 + 4];
    float4 h0 = *(const float4*)&stE[128 + fi * 8], h1 = *(const float4*)&stE[128 + fi * 8 + 4];
    su[0] = s0.x; su[1] = s0.y; su[2] = s0.z; su[3] = s0.w;
    su[4] = s1.x; su[5] = s1.y; su[6] = s1.z; su[7] = s1.w;
    hu[0] = h0.x; hu[1] = h0.y; hu[2] = h0.z; hu[3] = h0.w;
    hu[4] = h1.x; hu[5] = h1.y; hu[6] = h1.z; hu[7] = h1.w;
  }

  float sx[4] = {}, qx[4] = {};

  for (int node = waveId; node < n; node += nwaves) {
    int start = off[node], dg = deg[node];
    float num[8] = {}, den[8] = {};
    int k = qw;
    for (; k + 4 < dg; k += 8) {
      int p0 = start + k, p1 = start + k + 4;
      int id0 = list[p0], id1 = list[p1];
      int s0 = srcS[p0], s1 = srcS[p1];
      bf16x8 e0 = *(const bf16x8*)&eijS[(size_t)p0 * DD + fi * 8];   // streaming
      bf16x8 e1 = *(const bf16x8*)&eijS[(size_t)p1 * DD + fi * 8];
      bf16x8 b0 = *(const bf16x8*)&Bxh[(size_t)s0 * DD + fi * 8];
      bf16x8 b1 = *(const bf16x8*)&Bxh[(size_t)s1 * DD + fi * 8];
      float4 oa, ob, oc, od;
      float v0a[8], v1a[8];
      #pragma unroll
      for (int j = 0; j < 8; ++j) {
        float v0 = bf2f(e0[j]), v1 = bf2f(e1[j]);
        v0a[j] = fmaxf(0.f, v0 * su[j] + hu[j]);
        v1a[j] = fmaxf(0.f, v1 * su[j] + hu[j]);
        float g0 = 1.f / (1.f + __expf(-v0)), g1 = 1.f / (1.f + __expf(-v1));
        num[j] += g0 * bf2f(b0[j]) + g1 * bf2f(b1[j]);
        den[j] += g0 + g1;
      }
      oa.x = v0a[0]; oa.y = v0a[1]; oa.z = v0a[2]; oa.w = v0a[3];
      ob.x = v0a[4]; ob.y = v0a[5]; ob.z = v0a[6]; ob.w = v0a[7];
      oc.x = v1a[0]; oc.y = v1a[1]; oc.z = v1a[2]; oc.w = v1a[3];
      od.x = v1a[4]; od.y = v1a[5]; od.z = v1a[6]; od.w = v1a[7];
      *(float4*)&oute[(size_t)id0 * DD + fi * 8] = oa;
      *(float4*)&oute[(size_t)id0 * DD + fi * 8 + 4] = ob;
      *(float4*)&oute[(size_t)id1 * DD + fi * 8] = oc;
      *(float4*)&oute[(size_t)id1 * DD + fi * 8 + 4] = od;
    }
    for (; k < dg; k += 4) {
      int p0 = start + k;
      int id0 = list[p0];
      int s0 = srcS[p0];
      bf16x8 e0 = *(const bf16x8*)&eijS[(size_t)p0 * DD + fi * 8];
      bf16x8 b0 = *(const bf16x8*)&Bxh[(size_t)s0 * DD + fi * 8];
      float4 oa, ob;
      float v0a[8];
      #pragma unroll
      for (int j = 0; j < 8; ++j) {
        float v0 = bf2f(e0[j]);
        v0a[j] = fmaxf(0.f, v0 * su[j] + hu[j]);
        float g0 = 1.f / (1.f + __expf(-v0));
        num[j] += g0 * bf2f(b0[j]);
        den[j] += g0;
      }
      oa.x = v0a[0]; oa.y = v0a[1]; oa.z = v0a[2]; oa.w = v0a[3];
      ob.x = v0a[4]; ob.y = v0a[5]; ob.z = v0a[6]; ob.w = v0a[7];
      *(float4*)&oute[(size_t)id0 * DD + fi * 8] = oa;
      *(float4*)&oute[(size_t)id0 * DD + fi * 8 + 4] = ob;
    }
    #pragma unroll
    for (int j = 0; j < 8; ++j) {
      num[j] += __shfl_xor(num[j], 16); num[j] += __shfl_xor(num[j], 32);
      den[j] += __shfl_xor(den[j], 16); den[j] += __shfl_xor(den[j], 32);
    }
    if (qw < 2) {
      int c0 = fi * 8 + qw * 4;
      short4 ax = *(const short4*)&Axh[(size_t)node * DD + c0];
      short axa[4] = {ax.x, ax.y, ax.z, ax.w};
      float4 o;
      float vv[4];
      #pragma unroll
      for (int j = 0; j < 4; ++j) {
        int jj = qw * 4 + j;
        float aggr = num[jj] / (den[jj] + 1e-6f);
        float xp = bf2f(axa[j]) + aggr;
        vv[j] = xp;
        sx[j] += xp; qx[j] += xp * xp;
      }
      o.x = vv[0]; o.y = vv[1]; o.z = vv[2]; o.w = vv[3];
      *(float4*)&outx[(size_t)node * DD + c0] = o;
    }
  }

  __shared__ float lsX[4][128], lqX[4][128];
  if (qw < 2) {
    #pragma unroll
    for (int j = 0; j < 4; ++j) { lsX[w][fi * 8 + qw * 4 + j] = sx[j]; lqX[w][fi * 8 + qw * 4 + j] = qx[j]; }
  }
  __syncthreads();
  if (t < 128) {
    float a = lsX[0][t] + lsX[1][t] + lsX[2][t] + lsX[3][t];
    float b = lqX[0][t] + lqX[1][t] + lqX[2][t] + lqX[3][t];
    pX[(size_t)blockIdx.x * 256 + t] = a;
    pX[(size_t)blockIdx.x * 256 + 128 + t] = b;
  }
}

// reduce partials -> folded BN affine: stats[c]=scale, stats[128+c]=shift
__global__ __launch_bounds__(256) void k_reduce(const float* __restrict__ part, int nblk, float invcnt,
                                                const float* __restrict__ gamma, const float* __restrict__ beta,
                                                float* __restrict__ stats) {
  int c = blockIdx.x, t = threadIdx.x;
  float a = 0.f, b = 0.f;
  for (int k = t; k < nblk; k += 256) {
    a += part[(size_t)k * 256 + c];
    b += part[(size_t)k * 256 + 128 + c];
  }
  #pragma unroll
  for (int o = 32; o > 0; o >>= 1) { a += __shfl_down(a, o); b += __shfl_down(b, o); }
  __shared__ float ra[4], rb[4];
  int l = t & 63, w = t >> 6;
  if (l == 0) { ra[w] = a; rb[w] = b; }
  __syncthreads();
  if (t == 0) {
    a = ra[0] + ra[1] + ra[2] + ra[3];
    b = rb[0] + rb[1] + rb[2] + rb[3];
    float mean = a * invcnt;
    float var = b * invcnt - mean * mean;   // biased variance
    float istd = rsqrtf(var + 1e-5f);
    float scale = gamma[c] * istd;
    stats[c] = scale;
    stats[128 + c] = beta[c] - mean * scale;
  }
}

// ---------------- finalize x ----------------
__global__ __launch_bounds__(256) void k_xfinal(float* __restrict__ v, const float* __restrict__ st, size_t n4) {
  size_t i = (size_t)blockIdx.x * 256 + threadIdx.x;
  if (i >= n4) return;
  float4 d = *(const float4*)&v[i * 4];
  int f0 = (int)((i * 4) & 127);
  d.x = fmaxf(0.f, d.x * st[f0 + 0] + st[128 + f0 + 0]);
  d.y = fmaxf(0.f, d.y * st[f0 + 1] + st[128 + f0 + 1]);
  d.z = fmaxf(0.f, d.z * st[f0 + 2] + st[128 + f0 + 2]);
  d.w = fmaxf(0.f, d.w * st[f0 + 3] + st[128 + f0 + 3]);
  *(float4*)&v[i * 4] = d;
}

extern "C" void kernel_launch(void* const* d_in, const int* in_sizes, int n_in,
                              void* d_out, int out_size, void* d_ws, size_t ws_size,
                              hipStream_t stream) {
  const float* x  = (const float*)d_in[0];
  const float* e  = (const float*)d_in[1];
  const int*   ei = (const int*)d_in[2];
  const float* WA = (const float*)d_in[3];  const float* bA = (const float*)d_in[4];
  const float* WB = (const float*)d_in[5];  const float* bB = (const float*)d_in[6];
  const float* WC = (const float*)d_in[7];  const float* bC = (const float*)d_in[8];
  const float* WD = (const float*)d_in[9];  const float* bD = (const float*)d_in[10];
  const float* WE = (const float*)d_in[11]; const float* bE = (const float*)d_in[12];
  const float* gx = (const float*)d_in[13]; const float* bx = (const float*)d_in[14];
  const float* ge = (const float*)d_in[15]; const float* be = (const float*)d_in[16];

  int N = in_sizes[0] / DD;
  int E = in_sizes[2] / 2;
  const int* srcI = ei;       // edge_index[0]
  const int* dstI = ei + E;   // edge_index[1]

  float* outx = (float*)d_out;
  float* oute = (float*)d_out + (size_t)N * DD;

  int ntilesE = (E + 63) / 64;

  char* wp = (char*)d_ws;
  auto alloc = [&](size_t sz) { char* p = wp; wp += (sz + 255) & ~(size_t)255; return p; };
  short* Axh    = (short*)alloc((size_t)N * DD * 2);
  short* Bxh    = (short*)alloc((size_t)N * DD * 2);
  short* Dxh    = (short*)alloc((size_t)N * DD * 2);
  short* Exh    = (short*)alloc((size_t)N * DD * 2);
  short* eijS   = (short*)alloc((size_t)E * DD * 2);
  int*   deg    = (int*)alloc((size_t)N * 4);
  int*   off    = (int*)alloc((size_t)N * 4);
  int*   cursor = (int*)alloc((size_t)N * 4);
  int*   totals = (int*)alloc(1024);
  int*   boff   = (int*)alloc(1024);
  int*   list   = (int*)alloc((size_t)E * 4);
  int*   srcS   = (int*)alloc((size_t)E * 4);
  int*   posOf  = (int*)alloc((size_t)E * 4);
  float* pE     = (float*)alloc((size_t)GE * 256 * 4);
  float* pX     = (float*)alloc((size_t)NB_G * 256 * 4);
  float* statsE = (float*)alloc(1024);
  float* statsX = (float*)alloc(1024);
  short* WtA    = (short*)alloc((size_t)DD * DD * 2);
  short* WtB    = (short*)alloc((size_t)DD * DD * 2);
  short* WtC    = (short*)alloc((size_t)DD * DD * 2);
  short* WtD    = (short*)alloc((size_t)DD * DD * 2);
  short* WtE    = (short*)alloc((size_t)DD * DD * 2);
  (void)ws_size; (void)n_in; (void)out_size;

  int nsb = (N + 255) / 256;

  k_zero<<<nsb, 256, 0, stream>>>(deg, N);
  k_prewt5<<<5, 256, 0, stream>>>(WA, WB, WC, WD, WE, WtA, WtB, WtC, WtD, WtE);
  k_hist<<<(E + 255) / 256, 256, 0, stream>>>(dstI, deg, E);
  k_scan1<<<nsb, 256, 0, stream>>>(deg, off, totals, N);
  k_scan2<<<1, 256, 0, stream>>>(totals, boff, nsb);
  k_scan3<<<nsb, 256, 0, stream>>>(off, boff, cursor, N);
  k_fill<<<(E + 255) / 256, 256, 0, stream>>>(dstI, srcI, cursor, list, srcS, posOf, E);

  k_nodegemm<<<(N + 63) / 64, 256, 0, stream>>>(x, WtA, bA, WtB, bB, WtD, bD, WtE, bE,
                                                Axh, Bxh, Dxh, Exh, N);
  k_edge<<<GE, 256, 0, stream>>>(e, WtC, bC, srcI, dstI, posOf, Dxh, Exh, eijS, pE, E, ntilesE);
  k_reduce<<<128, 256, 0, stream>>>(pE, GE, 1.0f / (float)E, ge, be, statsE);

  k_gather<<<NB_G, 256, 0, stream>>>(off, deg, list, srcS, eijS, Bxh, Axh, statsE,
                                     outx, oute, pX, N);
  k_reduce<<<128, 256, 0, stream>>>(pX, NB_G, 1.0f / (float)N, gx, bx, statsX);
  k_xfinal<<<(int)(((size_t)N * DD / 4 + 255) / 256), 256, 0, stream>>>(outx, statsX, (size_t)N * DD / 4);
}

// Round 9
// 580.488 us; speedup vs baseline: 1.4342x; 1.0325x over previous
//
#include <hip/hip_runtime.h>
#include <stdint.h>

#define DD 128
#define NB_G 2048   // k_gather blocks
#define GE   2048   // k_edge persistent blocks

using f32x4  = __attribute__((ext_vector_type(4))) float;
using bf16x8 = __attribute__((ext_vector_type(8))) short;

__device__ __forceinline__ float bf2f(short u) {
  union { unsigned int i; float f; } c;
  c.i = ((unsigned int)(unsigned short)u) << 16;
  return c.f;
}
__device__ __forceinline__ short f2bf(float f) {
  union { float f; unsigned int i; } c;
  c.f = f;
  unsigned int u = c.i;
  u += 0x7fffu + ((u >> 16) & 1u);
  return (short)(u >> 16);
}

__global__ __launch_bounds__(256) void k_zero(int* __restrict__ p, int n) {
  int i = blockIdx.x * 256 + threadIdx.x;
  if (i < n) p[i] = 0;
}

// ---------------- CSR build ----------------
__global__ __launch_bounds__(256) void k_hist(const int* __restrict__ dst, int* __restrict__ deg, int E) {
  int e = blockIdx.x * 256 + threadIdx.x;
  if (e < E) atomicAdd(&deg[dst[e]], 1);
}

__global__ __launch_bounds__(256) void k_scan1(const int* __restrict__ deg, int* __restrict__ off,
                                               int* __restrict__ totals, int n) {
  __shared__ int sm[256];
  int t = threadIdx.x;
  int i = blockIdx.x * 256 + t;
  int v = (i < n) ? deg[i] : 0;
  sm[t] = v;
  __syncthreads();
  int acc = v;
  #pragma unroll
  for (int d = 1; d < 256; d <<= 1) {
    int add = (t >= d) ? sm[t - d] : 0;
    __syncthreads();
    acc += add;
    sm[t] = acc;
    __syncthreads();
  }
  if (i < n) off[i] = acc - v;          // exclusive
  if (t == 255) totals[blockIdx.x] = acc;
}

__global__ __launch_bounds__(256) void k_scan2(const int* __restrict__ totals, int* __restrict__ boff, int nb) {
  __shared__ int sm[256];
  int t = threadIdx.x;
  int v = (t < nb) ? totals[t] : 0;
  sm[t] = v;
  __syncthreads();
  int acc = v;
  #pragma unroll
  for (int d = 1; d < 256; d <<= 1) {
    int add = (t >= d) ? sm[t - d] : 0;
    __syncthreads();
    acc += add;
    sm[t] = acc;
    __syncthreads();
  }
  boff[t] = acc - v;
}

__global__ __launch_bounds__(256) void k_scan3(int* __restrict__ off, const int* __restrict__ boff,
                                               int* __restrict__ cursor, int n) {
  int i = blockIdx.x * 256 + threadIdx.x;
  if (i < n) {
    int o = off[i] + boff[blockIdx.x];
    off[i] = o;
    cursor[i] = o;
  }
}

__global__ __launch_bounds__(256) void k_fill(const int* __restrict__ dst, const int* __restrict__ src,
                                              int* __restrict__ cursor, int* __restrict__ list,
                                              int* __restrict__ srcS, int* __restrict__ posOf, int E) {
  int e = blockIdx.x * 256 + threadIdx.x;
  if (e < E) {
    int p = atomicAdd(&cursor[dst[e]], 1);
    list[p] = e;
    srcS[p] = src[e];
    posOf[e] = p;
  }
}

// ---------------- one-time weight convert+transpose: Wt[c][k] = bf16(W[k][c]) ----------------
__global__ __launch_bounds__(256) void k_prewt5(
    const float* __restrict__ WA, const float* __restrict__ WB, const float* __restrict__ WC,
    const float* __restrict__ WD, const float* __restrict__ WE,
    short* __restrict__ WtA, short* __restrict__ WtB, short* __restrict__ WtC,
    short* __restrict__ WtD, short* __restrict__ WtE) {
  const float* Ws[5] = {WA, WB, WC, WD, WE};
  short* Os[5] = {WtA, WtB, WtC, WtD, WtE};
  const float* W = Ws[blockIdx.x];
  short* O = Os[blockIdx.x];
  int t = threadIdx.x, c = t & 127, h = t >> 7;
  for (int p = 0; p < 8; ++p) {
    int k0 = (h * 8 + p) * 8;
    bf16x8 v;
    #pragma unroll
    for (int j = 0; j < 8; ++j) v[j] = f2bf(W[(size_t)(k0 + j) * DD + c]);
    *(bf16x8*)&O[(size_t)c * DD + k0] = v;
  }
}

// ---------------- node-side GEMMs (swapped MFMA; register-local epilogue) ----------
__global__ __launch_bounds__(256) void k_nodegemm(
    const float* __restrict__ x,
    const short* __restrict__ WtA, const float* __restrict__ bA,
    const short* __restrict__ WtB, const float* __restrict__ bB,
    const short* __restrict__ WtD, const float* __restrict__ bD,
    const short* __restrict__ WtE, const float* __restrict__ bE,
    short* __restrict__ Axh, short* __restrict__ Bxh,
    short* __restrict__ Dxh, short* __restrict__ Exh, int n) {
  int t = threadIdx.x;
  int w = t >> 6, l = t & 63, lg = l >> 4, lc = l & 15;
  int m0 = blockIdx.x * 64;
  int row = m0 + w * 16 + lc;
  bool valid = row < n;
  int rowc = valid ? row : n - 1;

  const float* xr = x + (size_t)rowc * DD;
  bf16x8 af[4];
  #pragma unroll
  for (int kk = 0; kk < 4; ++kk) {
    float4 a0 = *(const float4*)&xr[kk * 32 + lg * 8];
    float4 a1 = *(const float4*)&xr[kk * 32 + lg * 8 + 4];
    af[kk][0] = f2bf(a0.x); af[kk][1] = f2bf(a0.y); af[kk][2] = f2bf(a0.z); af[kk][3] = f2bf(a0.w);
    af[kk][4] = f2bf(a1.x); af[kk][5] = f2bf(a1.y); af[kk][6] = f2bf(a1.z); af[kk][7] = f2bf(a1.w);
  }

  const short* Wt[4] = {WtA, WtB, WtD, WtE};
  const float* bs[4] = {bA, bB, bD, bE};
  short* Os[4] = {Axh, Bxh, Dxh, Exh};

  #pragma unroll
  for (int mi = 0; mi < 4; ++mi) {
    const short* Wm = Wt[mi];
    f32x4 acc[8] = {};
    #pragma unroll
    for (int kk = 0; kk < 4; ++kk) {
      #pragma unroll
      for (int tt = 0; tt < 8; ++tt) {
        bf16x8 bfv = *(const bf16x8*)&Wm[(size_t)(tt * 16 + lc) * DD + kk * 32 + lg * 8];
        acc[tt] = __builtin_amdgcn_mfma_f32_16x16x32_bf16(bfv, af[kk], acc[tt], 0, 0, 0);
      }
    }
    if (valid) {
      short* O = Os[mi];
      #pragma unroll
      for (int tt = 0; tt < 8; ++tt) {
        int f0 = tt * 16 + lg * 4;
        float4 bc = *(const float4*)&bs[mi][f0];
        short4 o;
        o.x = f2bf(acc[tt][0] + bc.x);
        o.y = f2bf(acc[tt][1] + bc.y);
        o.z = f2bf(acc[tt][2] + bc.z);
        o.w = f2bf(acc[tt][3] + bc.w);
        *(short4*)&O[(size_t)row * DD + f0] = o;
      }
    }
  }
}

// ---------------- edge kernel: pipelined grid-stride; WtC staged once in LDS ----------------
// Ce GEMM + Dx[dst]+Ex[src]+bC -> eijS (CSR order); per-wave e-stat partials (no block reduce).
__global__ __launch_bounds__(256) void k_edge(
    const float* __restrict__ e, const short* __restrict__ WtC, const float* __restrict__ bC,
    const int* __restrict__ srcI, const int* __restrict__ dstI, const int* __restrict__ posOf,
    const short* __restrict__ Dxh, const short* __restrict__ Exh,
    short* __restrict__ eijS, float* __restrict__ pE, int Etot, int ntiles) {
  // fragment-major WtC: slot = tt*4+kk, 64 lanes x 16B contiguous per slot (conflict-free b128)
  __shared__ __align__(16) short lds_wt[32 * 64 * 8];       // 32 KB
  __shared__ __align__(16) short es[4][16][136];            // 17.4 KB per-wave restage
  int t = threadIdx.x;
  int w = t >> 6, l = t & 63, lg = l >> 4, lc = l & 15;

  // stage WtC -> LDS once per block (L1 no longer thrashes on MFMA-feeding loads)
  #pragma unroll
  for (int i = 0; i < 8; ++i) {
    int slot = w * 8 + i;
    int tt = slot >> 2, kk = slot & 3;
    bf16x8 v = *(const bf16x8*)&WtC[(size_t)(tt * 16 + lc) * DD + kk * 32 + lg * 8];
    *(bf16x8*)&lds_wt[(slot * 64 + l) * 8] = v;
  }
  __syncthreads();   // only barrier; tile loop below is barrier-free

  float bCv[8];
  #pragma unroll
  for (int tt = 0; tt < 8; ++tt) bCv[tt] = bC[tt * 16 + lc];

  float se[8] = {}, qe[8] = {};

  const int stride = gridDim.x;
  int tile = blockIdx.x;

  float4 e32[8];
  int dnN[4], snN[4], posN[4];

  // prefetch first tile
  {
    size_t m0 = (size_t)tile * 64;
    size_t row = m0 + w * 16 + lc;
    if (row >= (size_t)Etot) row = Etot - 1;
    const float* er = e + row * DD;
    #pragma unroll
    for (int kk = 0; kk < 4; ++kk) {
      e32[kk * 2]     = *(const float4*)&er[kk * 32 + lg * 8];
      e32[kk * 2 + 1] = *(const float4*)&er[kk * 32 + lg * 8 + 4];
    }
    #pragma unroll
    for (int z = 0; z < 4; ++z) {
      size_t erow = m0 + w * 16 + z * 4 + lg;
      if (erow >= (size_t)Etot) erow = Etot - 1;
      dnN[z] = dstI[erow]; snN[z] = srcI[erow]; posN[z] = posOf[erow];
    }
  }

  for (; tile < ntiles; tile += stride) {
    int dn[4], sn[4], pos[4];
    #pragma unroll
    for (int z = 0; z < 4; ++z) { dn[z] = dnN[z]; sn[z] = snN[z]; pos[z] = posN[z]; }

    // issue Dx/Ex row gathers for CURRENT tile (consumed in epilogue; overlap MFMA)
    bf16x8 dv[4], sv[4];
    #pragma unroll
    for (int z = 0; z < 4; ++z) {
      dv[z] = *(const bf16x8*)&Dxh[(size_t)dn[z] * DD + lc * 8];
      sv[z] = *(const bf16x8*)&Exh[(size_t)sn[z] * DD + lc * 8];
    }

    // convert current e-rows (loaded last iteration) to bf16 fragments
    bf16x8 af[4];
    #pragma unroll
    for (int kk = 0; kk < 4; ++kk) {
      float4 a0 = e32[kk * 2], a1 = e32[kk * 2 + 1];
      af[kk][0] = f2bf(a0.x); af[kk][1] = f2bf(a0.y); af[kk][2] = f2bf(a0.z); af[kk][3] = f2bf(a0.w);
      af[kk][4] = f2bf(a1.x); af[kk][5] = f2bf(a1.y); af[kk][6] = f2bf(a1.z); af[kk][7] = f2bf(a1.w);
    }

    // prefetch NEXT tile (e-rows f32 + epilogue indices)
    int nt = tile + stride;
    if (nt < ntiles) {
      size_t m0n = (size_t)nt * 64;
      size_t row = m0n + w * 16 + lc;
      if (row >= (size_t)Etot) row = Etot - 1;
      const float* er = e + row * DD;
      #pragma unroll
      for (int kk = 0; kk < 4; ++kk) {
        e32[kk * 2]     = *(const float4*)&er[kk * 32 + lg * 8];
        e32[kk * 2 + 1] = *(const float4*)&er[kk * 32 + lg * 8 + 4];
      }
      #pragma unroll
      for (int z = 0; z < 4; ++z) {
        size_t erow = m0n + w * 16 + z * 4 + lg;
        if (erow >= (size_t)Etot) erow = Etot - 1;
        dnN[z] = dstI[erow]; snN[z] = srcI[erow]; posN[z] = posOf[erow];
      }
    }

    // GEMM: B-fragments from LDS (ds_read_b128, lane-linear -> conflict-free)
    f32x4 acc[8] = {};
    #pragma unroll
    for (int kk = 0; kk < 4; ++kk) {
      #pragma unroll
      for (int tt = 0; tt < 8; ++tt) {
        bf16x8 bfv = *(const bf16x8*)&lds_wt[((tt * 4 + kk) * 64 + l) * 8];
        acc[tt] = __builtin_amdgcn_mfma_f32_16x16x32_bf16(af[kk], bfv, acc[tt], 0, 0, 0);
      }
    }

    // restage Ce+bC so epilogue rows are lane-contiguous
    #pragma unroll
    for (int tt = 0; tt < 8; ++tt) {
      int col = tt * 16 + lc;
      #pragma unroll
      for (int j = 0; j < 4; ++j)
        es[w][lg * 4 + j][col] = f2bf(acc[tt][j] + bCv[tt]);
    }
    asm volatile("s_waitcnt lgkmcnt(0)" ::: "memory");
    __builtin_amdgcn_sched_barrier(0);

    size_t m0 = (size_t)tile * 64;
    #pragma unroll
    for (int z = 0; z < 4; ++z) {
      size_t erow = m0 + w * 16 + z * 4 + lg;
      if (erow < (size_t)Etot) {
        int r = z * 4 + lg;
        bf16x8 cv = *(const bf16x8*)&es[w][r][lc * 8];
        bf16x8 o;
        #pragma unroll
        for (int j = 0; j < 8; ++j) {
          float v = bf2f(cv[j]) + bf2f(dv[z][j]) + bf2f(sv[z][j]);
          se[j] += v; qe[j] += v * v;
          o[j] = f2bf(v);
        }
        *(bf16x8*)&eijS[(size_t)pos[z] * DD + lc * 8] = o;
      }
    }
    __builtin_amdgcn_sched_barrier(0);
  }

  // per-wave stat partials (pE layout [GE*4][256]); no block reduce, no extra LDS
  #pragma unroll
  for (int j = 0; j < 8; ++j) {
    se[j] += __shfl_xor(se[j], 16); se[j] += __shfl_xor(se[j], 32);
    qe[j] += __shfl_xor(qe[j], 16); qe[j] += __shfl_xor(qe[j], 32);
  }
  if (lg == 0) {
    size_t base = ((size_t)blockIdx.x * 4 + w) * 256;
    #pragma unroll
    for (int j = 0; j < 8; ++j) {
      pE[base + lc * 8 + j] = se[j];
      pE[base + 128 + lc * 8 + j] = qe[j];
    }
  }
}

// ---------------- gather helper: one edge row -> BN+ReLU write + num/den accumulate ---------
__device__ __forceinline__ void proc_edge(int id, bf16x8 ev, bf16x8 bv,
                                          const float* su, const float* hu,
                                          float* num, float* den,
                                          float* __restrict__ oute, int fi) {
  float va[8];
  #pragma unroll
  for (int j = 0; j < 8; ++j) {
    float v0 = bf2f(ev[j]);
    va[j] = fmaxf(0.f, v0 * su[j] + hu[j]);
    float g0 = 1.f / (1.f + __expf(-v0));
    num[j] += g0 * bf2f(bv[j]);
    den[j] += g0;
  }
  float4 oa, ob;
  oa.x = va[0]; oa.y = va[1]; oa.z = va[2]; oa.w = va[3];
  ob.x = va[4]; ob.y = va[5]; ob.z = va[6]; ob.w = va[7];
  *(float4*)&oute[(size_t)id * DD + fi * 8] = oa;
  *(float4*)&oute[(size_t)id * DD + fi * 8 + 4] = ob;
}

// ---------------- gather: streaming CSR reads (4 chains/lane) + x_pre + fused e_out --------
__global__ __launch_bounds__(256) void k_gather(
    const int* __restrict__ off, const int* __restrict__ deg, const int* __restrict__ list,
    const int* __restrict__ srcS, const short* __restrict__ eijS, const short* __restrict__ Bxh,
    const short* __restrict__ Axh, const float* __restrict__ stE,
    float* __restrict__ outx, float* __restrict__ oute,
    float* __restrict__ pX, int n) {
  int t = threadIdx.x;
  int w = t >> 6, l = t & 63;
  int qw = l >> 4, fi = l & 15;
  int waveId = blockIdx.x * 4 + w;
  const int nwaves = NB_G * 4;

  float su[8], hu[8];
  {
    float4 s0 = *(const float4*)&stE[fi * 8], s1 = *(const float4*)&stE[fi * 8 + 4];
    float4 h0 = *(const float4*)&stE[128 + fi * 8], h1 = *(const float4*)&stE[128 + fi * 8 + 4];
    su[0] = s0.x; su[1] = s0.y; su[2] = s0.z; su[3] = s0.w;
    su[4] = s1.x; su[5] = s1.y; su[6] = s1.z; su[7] = s1.w;
    hu[0] = h0.x; hu[1] = h0.y; hu[2] = h0.z; hu[3] = h0.w;
    hu[4] = h1.x; hu[5] = h1.y; hu[6] = h1.z; hu[7] = h1.w;
  }

  float sx[4] = {}, qx[4] = {};

  for (int node = waveId; node < n; node += nwaves) {
    int start = off[node], dg = deg[node];
    float num[8] = {}, den[8] = {};
    int k = qw;
    // 4 independent load chains per lane (deg~16 -> single pass for the common case)
    for (; k + 12 < dg; k += 16) {
      int p0 = start + k, p1 = p0 + 4, p2 = p0 + 8, p3 = p0 + 12;
      int id0 = list[p0], id1 = list[p1], id2 = list[p2], id3 = list[p3];
      int s0 = srcS[p0], s1 = srcS[p1], s2 = srcS[p2], s3 = srcS[p3];
      bf16x8 e0 = *(const bf16x8*)&eijS[(size_t)p0 * DD + fi * 8];
      bf16x8 e1 = *(const bf16x8*)&eijS[(size_t)p1 * DD + fi * 8];
      bf16x8 e2 = *(const bf16x8*)&eijS[(size_t)p2 * DD + fi * 8];
      bf16x8 e3 = *(const bf16x8*)&eijS[(size_t)p3 * DD + fi * 8];
      bf16x8 b0 = *(const bf16x8*)&Bxh[(size_t)s0 * DD + fi * 8];
      bf16x8 b1 = *(const bf16x8*)&Bxh[(size_t)s1 * DD + fi * 8];
      bf16x8 b2 = *(const bf16x8*)&Bxh[(size_t)s2 * DD + fi * 8];
      bf16x8 b3 = *(const bf16x8*)&Bxh[(size_t)s3 * DD + fi * 8];
      proc_edge(id0, e0, b0, su, hu, num, den, oute, fi);
      proc_edge(id1, e1, b1, su, hu, num, den, oute, fi);
      proc_edge(id2, e2, b2, su, hu, num, den, oute, fi);
      proc_edge(id3, e3, b3, su, hu, num, den, oute, fi);
    }
    for (; k < dg; k += 4) {
      int p0 = start + k;
      int id0 = list[p0];
      int s0 = srcS[p0];
      bf16x8 e0 = *(const bf16x8*)&eijS[(size_t)p0 * DD + fi * 8];
      bf16x8 b0 = *(const bf16x8*)&Bxh[(size_t)s0 * DD + fi * 8];
      proc_edge(id0, e0, b0, su, hu, num, den, oute, fi);
    }
    #pragma unroll
    for (int j = 0; j < 8; ++j) {
      num[j] += __shfl_xor(num[j], 16); num[j] += __shfl_xor(num[j], 32);
      den[j] += __shfl_xor(den[j], 16); den[j] += __shfl_xor(den[j], 32);
    }
    if (qw < 2) {
      int c0 = fi * 8 + qw * 4;
      short4 ax = *(const short4*)&Axh[(size_t)node * DD + c0];
      short axa[4] = {ax.x, ax.y, ax.z, ax.w};
      float4 o;
      float vv[4];
      #pragma unroll
      for (int j = 0; j < 4; ++j) {
        int jj = qw * 4 + j;
        float aggr = num[jj] / (den[jj] + 1e-6f);
        float xp = bf2f(axa[j]) + aggr;
        vv[j] = xp;
        sx[j] += xp; qx[j] += xp * xp;
      }
      o.x = vv[0]; o.y = vv[1]; o.z = vv[2]; o.w = vv[3];
      *(float4*)&outx[(size_t)node * DD + c0] = o;
    }
  }

  __shared__ float lsX[4][128], lqX[4][128];
  if (qw < 2) {
    #pragma unroll
    for (int j = 0; j < 4; ++j) { lsX[w][fi * 8 + qw * 4 + j] = sx[j]; lqX[w][fi * 8 + qw * 4 + j] = qx[j]; }
  }
  __syncthreads();
  if (t < 128) {
    float a = lsX[0][t] + lsX[1][t] + lsX[2][t] + lsX[3][t];
    float b = lqX[0][t] + lqX[1][t] + lqX[2][t] + lqX[3][t];
    pX[(size_t)blockIdx.x * 256 + t] = a;
    pX[(size_t)blockIdx.x * 256 + 128 + t] = b;
  }
}

// reduce partials -> folded BN affine: stats[c]=scale, stats[128+c]=shift
__global__ __launch_bounds__(256) void k_reduce(const float* __restrict__ part, int nblk, float invcnt,
                                                const float* __restrict__ gamma, const float* __restrict__ beta,
                                                float* __restrict__ stats) {
  int c = blockIdx.x, t = threadIdx.x;
  float a = 0.f, b = 0.f;
  for (int k = t; k < nblk; k += 256) {
    a += part[(size_t)k * 256 + c];
    b += part[(size_t)k * 256 + 128 + c];
  }
  #pragma unroll
  for (int o = 32; o > 0; o >>= 1) { a += __shfl_down(a, o); b += __shfl_down(b, o); }
  __shared__ float ra[4], rb[4];
  int l = t & 63, w = t >> 6;
  if (l == 0) { ra[w] = a; rb[w] = b; }
  __syncthreads();
  if (t == 0) {
    a = ra[0] + ra[1] + ra[2] + ra[3];
    b = rb[0] + rb[1] + rb[2] + rb[3];
    float mean = a * invcnt;
    float var = b * invcnt - mean * mean;   // biased variance
    float istd = rsqrtf(var + 1e-5f);
    float scale = gamma[c] * istd;
    stats[c] = scale;
    stats[128 + c] = beta[c] - mean * scale;
  }
}

// ---------------- finalize x ----------------
__global__ __launch_bounds__(256) void k_xfinal(float* __restrict__ v, const float* __restrict__ st, size_t n4) {
  size_t i = (size_t)blockIdx.x * 256 + threadIdx.x;
  if (i >= n4) return;
  float4 d = *(const float4*)&v[i * 4];
  int f0 = (int)((i * 4) & 127);
  d.x = fmaxf(0.f, d.x * st[f0 + 0] + st[128 + f0 + 0]);
  d.y = fmaxf(0.f, d.y * st[f0 + 1] + st[128 + f0 + 1]);
  d.z = fmaxf(0.f, d.z * st[f0 + 2] + st[128 + f0 + 2]);
  d.w = fmaxf(0.f, d.w * st[f0 + 3] + st[128 + f0 + 3]);
  *(float4*)&v[i * 4] = d;
}

extern "C" void kernel_launch(void* const* d_in, const int* in_sizes, int n_in,
                              void* d_out, int out_size, void* d_ws, size_t ws_size,
                              hipStream_t stream) {
  const float* x  = (const float*)d_in[0];
  const float* e  = (const float*)d_in[1];
  const int*   ei = (const int*)d_in[2];
  const float* WA = (const float*)d_in[3];  const float* bA = (const float*)d_in[4];
  const float* WB = (const float*)d_in[5];  const float* bB = (const float*)d_in[6];
  const float* WC = (const float*)d_in[7];  const float* bC = (const float*)d_in[8];
  const float* WD = (const float*)d_in[9];  const float* bD = (const float*)d_in[10];
  const float* WE = (const float*)d_in[11]; const float* bE = (const float*)d_in[12];
  const float* gx = (const float*)d_in[13]; const float* bx = (const float*)d_in[14];
  const float* ge = (const float*)d_in[15]; const float* be = (const float*)d_in[16];

  int N = in_sizes[0] / DD;
  int E = in_sizes[2] / 2;
  const int* srcI = ei;       // edge_index[0]
  const int* dstI = ei + E;   // edge_index[1]

  float* outx = (float*)d_out;
  float* oute = (float*)d_out + (size_t)N * DD;

  int ntilesE = (E + 63) / 64;

  char* wp = (char*)d_ws;
  auto alloc = [&](size_t sz) { char* p = wp; wp += (sz + 255) & ~(size_t)255; return p; };
  short* Axh    = (short*)alloc((size_t)N * DD * 2);
  short* Bxh    = (short*)alloc((size_t)N * DD * 2);
  short* Dxh    = (short*)alloc((size_t)N * DD * 2);
  short* Exh    = (short*)alloc((size_t)N * DD * 2);
  short* eijS   = (short*)alloc((size_t)E * DD * 2);
  int*   deg    = (int*)alloc((size_t)N * 4);
  int*   off    = (int*)alloc((size_t)N * 4);
  int*   cursor = (int*)alloc((size_t)N * 4);
  int*   totals = (int*)alloc(1024);
  int*   boff   = (int*)alloc(1024);
  int*   list   = (int*)alloc((size_t)E * 4);
  int*   srcS   = (int*)alloc((size_t)E * 4);
  int*   posOf  = (int*)alloc((size_t)E * 4);
  float* pE     = (float*)alloc((size_t)GE * 4 * 256 * 4);   // per-wave partials
  float* pX     = (float*)alloc((size_t)NB_G * 256 * 4);
  float* statsE = (float*)alloc(1024);
  float* statsX = (float*)alloc(1024);
  short* WtA    = (short*)alloc((size_t)DD * DD * 2);
  short* WtB    = (short*)alloc((size_t)DD * DD * 2);
  short* WtC    = (short*)alloc((size_t)DD * DD * 2);
  short* WtD    = (short*)alloc((size_t)DD * DD * 2);
  short* WtE    = (short*)alloc((size_t)DD * DD * 2);
  (void)ws_size; (void)n_in; (void)out_size;

  int nsb = (N + 255) / 256;

  k_zero<<<nsb, 256, 0, stream>>>(deg, N);
  k_prewt5<<<5, 256, 0, stream>>>(WA, WB, WC, WD, WE, WtA, WtB, WtC, WtD, WtE);
  k_hist<<<(E + 255) / 256, 256, 0, stream>>>(dstI, deg, E);
  k_scan1<<<nsb, 256, 0, stream>>>(deg, off, totals, N);
  k_scan2<<<1, 256, 0, stream>>>(totals, boff, nsb);
  k_scan3<<<nsb, 256, 0, stream>>>(off, boff, cursor, N);
  k_fill<<<(E + 255) / 256, 256, 0, stream>>>(dstI, srcI, cursor, list, srcS, posOf, E);

  k_nodegemm<<<(N + 63) / 64, 256, 0, stream>>>(x, WtA, bA, WtB, bB, WtD, bD, WtE, bE,
                                                Axh, Bxh, Dxh, Exh, N);
  k_edge<<<GE, 256, 0, stream>>>(e, WtC, bC, srcI, dstI, posOf, Dxh, Exh, eijS, pE, E, ntilesE);
  k_reduce<<<128, 256, 0, stream>>>(pE, GE * 4, 1.0f / (float)E, ge, be, statsE);

  k_gather<<<NB_G, 256, 0, stream>>>(off, deg, list, srcS, eijS, Bxh, Axh, statsE,
                                     outx, oute, pX, N);
  k_reduce<<<128, 256, 0, stream>>>(pX, NB_G, 1.0f / (float)N, gx, bx, statsX);
  k_xfinal<<<(int)(((size_t)N * DD / 4 + 255) / 256), 256, 0, stream>>>(outx, statsX, (size_t)N * DD / 4);
}

// Round 10
// 566.718 us; speedup vs baseline: 1.4691x; 1.0243x over previous
//
#include <hip/hip_runtime.h>
#include <stdint.h>

#define DD 128
#define NB_G 2048   // k_gather blocks
#define GE   2048   // k_edge persistent blocks

using f32x4  = __attribute__((ext_vector_type(4))) float;
using bf16x8 = __attribute__((ext_vector_type(8))) short;

__device__ __forceinline__ float bf2f(short u) {
  union { unsigned int i; float f; } c;
  c.i = ((unsigned int)(unsigned short)u) << 16;
  return c.f;
}
__device__ __forceinline__ short f2bf(float f) {
  union { float f; unsigned int i; } c;
  c.f = f;
  unsigned int u = c.i;
  u += 0x7fffu + ((u >> 16) & 1u);
  return (short)(u >> 16);
}

// ---------------- prep: weight convert+transpose (blocks 0-4) + zero deg (blocks 5+) --------
__global__ __launch_bounds__(256) void k_prep(
    const float* __restrict__ WA, const float* __restrict__ WB, const float* __restrict__ WC,
    const float* __restrict__ WD, const float* __restrict__ WE,
    short* __restrict__ WtA, short* __restrict__ WtB, short* __restrict__ WtC,
    short* __restrict__ WtD, short* __restrict__ WtE,
    int* __restrict__ deg, int n) {
  int t = threadIdx.x;
  if (blockIdx.x < 5) {
    const float* Ws[5] = {WA, WB, WC, WD, WE};
    short* Os[5] = {WtA, WtB, WtC, WtD, WtE};
    const float* W = Ws[blockIdx.x];
    short* O = Os[blockIdx.x];
    int c = t & 127, h = t >> 7;
    for (int p = 0; p < 8; ++p) {
      int k0 = (h * 8 + p) * 8;
      bf16x8 v;
      #pragma unroll
      for (int j = 0; j < 8; ++j) v[j] = f2bf(W[(size_t)(k0 + j) * DD + c]);
      *(bf16x8*)&O[(size_t)c * DD + k0] = v;
    }
  } else {
    int i = (blockIdx.x - 5) * 256 + t;
    if (i < n) deg[i] = 0;
  }
}

// ---------------- CSR build ----------------
__global__ __launch_bounds__(256) void k_hist(const int* __restrict__ dst, int* __restrict__ deg, int E) {
  int e = blockIdx.x * 256 + threadIdx.x;
  if (e < E) atomicAdd(&deg[dst[e]], 1);
}

__global__ __launch_bounds__(256) void k_scan1(const int* __restrict__ deg, int* __restrict__ off,
                                               int* __restrict__ totals, int n) {
  __shared__ int sm[256];
  int t = threadIdx.x;
  int i = blockIdx.x * 256 + t;
  int v = (i < n) ? deg[i] : 0;
  sm[t] = v;
  __syncthreads();
  int acc = v;
  #pragma unroll
  for (int d = 1; d < 256; d <<= 1) {
    int add = (t >= d) ? sm[t - d] : 0;
    __syncthreads();
    acc += add;
    sm[t] = acc;
    __syncthreads();
  }
  if (i < n) off[i] = acc - v;          // exclusive
  if (t == 255) totals[blockIdx.x] = acc;
}

__global__ __launch_bounds__(256) void k_scan2(const int* __restrict__ totals, int* __restrict__ boff, int nb) {
  __shared__ int sm[256];
  int t = threadIdx.x;
  int v = (t < nb) ? totals[t] : 0;
  sm[t] = v;
  __syncthreads();
  int acc = v;
  #pragma unroll
  for (int d = 1; d < 256; d <<= 1) {
    int add = (t >= d) ? sm[t - d] : 0;
    __syncthreads();
    acc += add;
    sm[t] = acc;
    __syncthreads();
  }
  boff[t] = acc - v;
}

__global__ __launch_bounds__(256) void k_scan3(int* __restrict__ off, const int* __restrict__ boff,
                                               int* __restrict__ cursor, int n) {
  int i = blockIdx.x * 256 + threadIdx.x;
  if (i < n) {
    int o = off[i] + boff[blockIdx.x];
    off[i] = o;
    cursor[i] = o;
  }
}

__global__ __launch_bounds__(256) void k_fill(const int* __restrict__ dst, const int* __restrict__ src,
                                              int* __restrict__ cursor, int* __restrict__ list,
                                              int* __restrict__ srcS, int* __restrict__ posOf, int E) {
  int e = blockIdx.x * 256 + threadIdx.x;
  if (e < E) {
    int p = atomicAdd(&cursor[dst[e]], 1);
    list[p] = e;
    srcS[p] = src[e];
    posOf[e] = p;
  }
}

// ---------------- node-side GEMMs (swapped MFMA; register-local epilogue) ----------
__global__ __launch_bounds__(256) void k_nodegemm(
    const float* __restrict__ x,
    const short* __restrict__ WtA, const float* __restrict__ bA,
    const short* __restrict__ WtB, const float* __restrict__ bB,
    const short* __restrict__ WtD, const float* __restrict__ bD,
    const short* __restrict__ WtE, const float* __restrict__ bE,
    short* __restrict__ Axh, short* __restrict__ Bxh,
    short* __restrict__ Dxh, short* __restrict__ Exh, int n) {
  int t = threadIdx.x;
  int w = t >> 6, l = t & 63, lg = l >> 4, lc = l & 15;
  int m0 = blockIdx.x * 64;
  int row = m0 + w * 16 + lc;
  bool valid = row < n;
  int rowc = valid ? row : n - 1;

  const float* xr = x + (size_t)rowc * DD;
  bf16x8 af[4];
  #pragma unroll
  for (int kk = 0; kk < 4; ++kk) {
    float4 a0 = *(const float4*)&xr[kk * 32 + lg * 8];
    float4 a1 = *(const float4*)&xr[kk * 32 + lg * 8 + 4];
    af[kk][0] = f2bf(a0.x); af[kk][1] = f2bf(a0.y); af[kk][2] = f2bf(a0.z); af[kk][3] = f2bf(a0.w);
    af[kk][4] = f2bf(a1.x); af[kk][5] = f2bf(a1.y); af[kk][6] = f2bf(a1.z); af[kk][7] = f2bf(a1.w);
  }

  const short* Wt[4] = {WtA, WtB, WtD, WtE};
  const float* bs[4] = {bA, bB, bD, bE};
  short* Os[4] = {Axh, Bxh, Dxh, Exh};

  #pragma unroll
  for (int mi = 0; mi < 4; ++mi) {
    const short* Wm = Wt[mi];
    f32x4 acc[8] = {};
    #pragma unroll
    for (int kk = 0; kk < 4; ++kk) {
      #pragma unroll
      for (int tt = 0; tt < 8; ++tt) {
        bf16x8 bfv = *(const bf16x8*)&Wm[(size_t)(tt * 16 + lc) * DD + kk * 32 + lg * 8];
        acc[tt] = __builtin_amdgcn_mfma_f32_16x16x32_bf16(bfv, af[kk], acc[tt], 0, 0, 0);
      }
    }
    if (valid) {
      short* O = Os[mi];
      #pragma unroll
      for (int tt = 0; tt < 8; ++tt) {
        int f0 = tt * 16 + lg * 4;
        float4 bc = *(const float4*)&bs[mi][f0];
        short4 o;
        o.x = f2bf(acc[tt][0] + bc.x);
        o.y = f2bf(acc[tt][1] + bc.y);
        o.z = f2bf(acc[tt][2] + bc.z);
        o.w = f2bf(acc[tt][3] + bc.w);
        *(short4*)&O[(size_t)row * DD + f0] = o;
      }
    }
  }
}

// ---------------- edge kernel: pipelined grid-stride; WtC staged once in LDS ----------------
__global__ __launch_bounds__(256) void k_edge(
    const float* __restrict__ e, const short* __restrict__ WtC, const float* __restrict__ bC,
    const int* __restrict__ srcI, const int* __restrict__ dstI, const int* __restrict__ posOf,
    const short* __restrict__ Dxh, const short* __restrict__ Exh,
    short* __restrict__ eijS, float* __restrict__ pE, int Etot, int ntiles) {
  __shared__ __align__(16) short lds_wt[32 * 64 * 8];       // 32 KB fragment-major WtC
  __shared__ __align__(16) short es[4][16][136];            // per-wave restage
  int t = threadIdx.x;
  int w = t >> 6, l = t & 63, lg = l >> 4, lc = l & 15;

  #pragma unroll
  for (int i = 0; i < 8; ++i) {
    int slot = w * 8 + i;
    int tt = slot >> 2, kk = slot & 3;
    bf16x8 v = *(const bf16x8*)&WtC[(size_t)(tt * 16 + lc) * DD + kk * 32 + lg * 8];
    *(bf16x8*)&lds_wt[(slot * 64 + l) * 8] = v;
  }
  __syncthreads();

  float bCv[8];
  #pragma unroll
  for (int tt = 0; tt < 8; ++tt) bCv[tt] = bC[tt * 16 + lc];

  float se[8] = {}, qe[8] = {};

  const int stride = gridDim.x;
  int tile = blockIdx.x;

  float4 e32[8];
  int dnN[4], snN[4], posN[4];

  {
    size_t m0 = (size_t)tile * 64;
    size_t row = m0 + w * 16 + lc;
    if (row >= (size_t)Etot) row = Etot - 1;
    const float* er = e + row * DD;
    #pragma unroll
    for (int kk = 0; kk < 4; ++kk) {
      e32[kk * 2]     = *(const float4*)&er[kk * 32 + lg * 8];
      e32[kk * 2 + 1] = *(const float4*)&er[kk * 32 + lg * 8 + 4];
    }
    #pragma unroll
    for (int z = 0; z < 4; ++z) {
      size_t erow = m0 + w * 16 + z * 4 + lg;
      if (erow >= (size_t)Etot) erow = Etot - 1;
      dnN[z] = dstI[erow]; snN[z] = srcI[erow]; posN[z] = posOf[erow];
    }
  }

  for (; tile < ntiles; tile += stride) {
    int dn[4], sn[4], pos[4];
    #pragma unroll
    for (int z = 0; z < 4; ++z) { dn[z] = dnN[z]; sn[z] = snN[z]; pos[z] = posN[z]; }

    bf16x8 dv[4], sv[4];
    #pragma unroll
    for (int z = 0; z < 4; ++z) {
      dv[z] = *(const bf16x8*)&Dxh[(size_t)dn[z] * DD + lc * 8];
      sv[z] = *(const bf16x8*)&Exh[(size_t)sn[z] * DD + lc * 8];
    }

    bf16x8 af[4];
    #pragma unroll
    for (int kk = 0; kk < 4; ++kk) {
      float4 a0 = e32[kk * 2], a1 = e32[kk * 2 + 1];
      af[kk][0] = f2bf(a0.x); af[kk][1] = f2bf(a0.y); af[kk][2] = f2bf(a0.z); af[kk][3] = f2bf(a0.w);
      af[kk][4] = f2bf(a1.x); af[kk][5] = f2bf(a1.y); af[kk][6] = f2bf(a1.z); af[kk][7] = f2bf(a1.w);
    }

    int nt = tile + stride;
    if (nt < ntiles) {
      size_t m0n = (size_t)nt * 64;
      size_t row = m0n + w * 16 + lc;
      if (row >= (size_t)Etot) row = Etot - 1;
      const float* er = e + row * DD;
      #pragma unroll
      for (int kk = 0; kk < 4; ++kk) {
        e32[kk * 2]     = *(const float4*)&er[kk * 32 + lg * 8];
        e32[kk * 2 + 1] = *(const float4*)&er[kk * 32 + lg * 8 + 4];
      }
      #pragma unroll
      for (int z = 0; z < 4; ++z) {
        size_t erow = m0n + w * 16 + z * 4 + lg;
        if (erow >= (size_t)Etot) erow = Etot - 1;
        dnN[z] = dstI[erow]; snN[z] = srcI[erow]; posN[z] = posOf[erow];
      }
    }

    f32x4 acc[8] = {};
    #pragma unroll
    for (int kk = 0; kk < 4; ++kk) {
      #pragma unroll
      for (int tt = 0; tt < 8; ++tt) {
        bf16x8 bfv = *(const bf16x8*)&lds_wt[((tt * 4 + kk) * 64 + l) * 8];
        acc[tt] = __builtin_amdgcn_mfma_f32_16x16x32_bf16(af[kk], bfv, acc[tt], 0, 0, 0);
      }
    }

    #pragma unroll
    for (int tt = 0; tt < 8; ++tt) {
      int col = tt * 16 + lc;
      #pragma unroll
      for (int j = 0; j < 4; ++j)
        es[w][lg * 4 + j][col] = f2bf(acc[tt][j] + bCv[tt]);
    }
    asm volatile("s_waitcnt lgkmcnt(0)" ::: "memory");
    __builtin_amdgcn_sched_barrier(0);

    size_t m0 = (size_t)tile * 64;
    #pragma unroll
    for (int z = 0; z < 4; ++z) {
      size_t erow = m0 + w * 16 + z * 4 + lg;
      if (erow < (size_t)Etot) {
        int r = z * 4 + lg;
        bf16x8 cv = *(const bf16x8*)&es[w][r][lc * 8];
        bf16x8 o;
        #pragma unroll
        for (int j = 0; j < 8; ++j) {
          float v = bf2f(cv[j]) + bf2f(dv[z][j]) + bf2f(sv[z][j]);
          se[j] += v; qe[j] += v * v;
          o[j] = f2bf(v);
        }
        *(bf16x8*)&eijS[(size_t)pos[z] * DD + lc * 8] = o;
      }
    }
    __builtin_amdgcn_sched_barrier(0);
  }

  #pragma unroll
  for (int j = 0; j < 8; ++j) {
    se[j] += __shfl_xor(se[j], 16); se[j] += __shfl_xor(se[j], 32);
    qe[j] += __shfl_xor(qe[j], 16); qe[j] += __shfl_xor(qe[j], 32);
  }
  if (lg == 0) {
    size_t base = ((size_t)blockIdx.x * 4 + w) * 256;
    #pragma unroll
    for (int j = 0; j < 8; ++j) {
      pE[base + lc * 8 + j] = se[j];
      pE[base + 128 + lc * 8 + j] = qe[j];
    }
  }
}

// ---------------- gather helper ----------------
__device__ __forceinline__ void proc_edge(int id, bf16x8 ev, bf16x8 bv,
                                          const float* su, const float* hu,
                                          float* num, float* den,
                                          float* __restrict__ oute, int fi) {
  float va[8];
  #pragma unroll
  for (int j = 0; j < 8; ++j) {
    float v0 = bf2f(ev[j]);
    va[j] = fmaxf(0.f, v0 * su[j] + hu[j]);
    float g0 = 1.f / (1.f + __expf(-v0));
    num[j] += g0 * bf2f(bv[j]);
    den[j] += g0;
  }
  float4 oa, ob;
  oa.x = va[0]; oa.y = va[1]; oa.z = va[2]; oa.w = va[3];
  ob.x = va[4]; ob.y = va[5]; ob.z = va[6]; ob.w = va[7];
  *(float4*)&oute[(size_t)id * DD + fi * 8] = oa;
  *(float4*)&oute[(size_t)id * DD + fi * 8 + 4] = ob;
}

// ---------------- gather: 16/8/4-chain loops, node-level prefetch, bf16 x_pre --------------
__global__ __launch_bounds__(256) void k_gather(
    const int* __restrict__ off, const int* __restrict__ deg, const int* __restrict__ list,
    const int* __restrict__ srcS, const short* __restrict__ eijS, const short* __restrict__ Bxh,
    const short* __restrict__ Axh, const float* __restrict__ stE,
    short* __restrict__ outxh, float* __restrict__ oute,
    float* __restrict__ pX, int n) {
  int t = threadIdx.x;
  int w = t >> 6, l = t & 63;
  int qw = l >> 4, fi = l & 15;
  int waveId = blockIdx.x * 4 + w;
  const int nwaves = NB_G * 4;

  float su[8], hu[8];
  {
    float4 s0 = *(const float4*)&stE[fi * 8], s1 = *(const float4*)&stE[fi * 8 + 4];
    float4 h0 = *(const float4*)&stE[128 + fi * 8], h1 = *(const float4*)&stE[128 + fi * 8 + 4];
    su[0] = s0.x; su[1] = s0.y; su[2] = s0.z; su[3] = s0.w;
    su[4] = s1.x; su[5] = s1.y; su[6] = s1.z; su[7] = s1.w;
    hu[0] = h0.x; hu[1] = h0.y; hu[2] = h0.z; hu[3] = h0.w;
    hu[4] = h1.x; hu[5] = h1.y; hu[6] = h1.z; hu[7] = h1.w;
  }

  float sx[4] = {}, qx[4] = {};
  int c0 = fi * 8 + ((qw & 1) * 4);   // valid col for qw<2; harmless otherwise

  int startC = 0, dgC = 0;
  if (waveId < n) { startC = off[waveId]; dgC = deg[waveId]; }

  for (int node = waveId; node < n; node += nwaves) {
    int start = startC, dg = dgC;
    // prefetch next node's off/deg (kills per-node serial stall)
    int nn = node + nwaves;
    if (nn < n) { startC = off[nn]; dgC = deg[nn]; }
    // hoist Axh row load (consumed after reduction)
    short4 ax = *(const short4*)&Axh[(size_t)node * DD + (qw < 2 ? c0 : fi * 8)];

    float num[8] = {}, den[8] = {};
    int k = qw;
    for (; k + 12 < dg; k += 16) {   // 4 chains/lane
      int p0 = start + k, p1 = p0 + 4, p2 = p0 + 8, p3 = p0 + 12;
      int id0 = list[p0], id1 = list[p1], id2 = list[p2], id3 = list[p3];
      int s0 = srcS[p0], s1 = srcS[p1], s2 = srcS[p2], s3 = srcS[p3];
      bf16x8 e0 = *(const bf16x8*)&eijS[(size_t)p0 * DD + fi * 8];
      bf16x8 e1 = *(const bf16x8*)&eijS[(size_t)p1 * DD + fi * 8];
      bf16x8 e2 = *(const bf16x8*)&eijS[(size_t)p2 * DD + fi * 8];
      bf16x8 e3 = *(const bf16x8*)&eijS[(size_t)p3 * DD + fi * 8];
      bf16x8 b0 = *(const bf16x8*)&Bxh[(size_t)s0 * DD + fi * 8];
      bf16x8 b1 = *(const bf16x8*)&Bxh[(size_t)s1 * DD + fi * 8];
      bf16x8 b2 = *(const bf16x8*)&Bxh[(size_t)s2 * DD + fi * 8];
      bf16x8 b3 = *(const bf16x8*)&Bxh[(size_t)s3 * DD + fi * 8];
      proc_edge(id0, e0, b0, su, hu, num, den, oute, fi);
      proc_edge(id1, e1, b1, su, hu, num, den, oute, fi);
      proc_edge(id2, e2, b2, su, hu, num, den, oute, fi);
      proc_edge(id3, e3, b3, su, hu, num, den, oute, fi);
    }
    for (; k + 4 < dg; k += 8) {     // 2 chains/lane
      int p0 = start + k, p1 = p0 + 4;
      int id0 = list[p0], id1 = list[p1];
      int s0 = srcS[p0], s1 = srcS[p1];
      bf16x8 e0 = *(const bf16x8*)&eijS[(size_t)p0 * DD + fi * 8];
      bf16x8 e1 = *(const bf16x8*)&eijS[(size_t)p1 * DD + fi * 8];
      bf16x8 b0 = *(const bf16x8*)&Bxh[(size_t)s0 * DD + fi * 8];
      bf16x8 b1 = *(const bf16x8*)&Bxh[(size_t)s1 * DD + fi * 8];
      proc_edge(id0, e0, b0, su, hu, num, den, oute, fi);
      proc_edge(id1, e1, b1, su, hu, num, den, oute, fi);
    }
    for (; k < dg; k += 4) {         // 1 chain
      int p0 = start + k;
      int id0 = list[p0];
      int s0 = srcS[p0];
      bf16x8 e0 = *(const bf16x8*)&eijS[(size_t)p0 * DD + fi * 8];
      bf16x8 b0 = *(const bf16x8*)&Bxh[(size_t)s0 * DD + fi * 8];
      proc_edge(id0, e0, b0, su, hu, num, den, oute, fi);
    }
    #pragma unroll
    for (int j = 0; j < 8; ++j) {
      num[j] += __shfl_xor(num[j], 16); num[j] += __shfl_xor(num[j], 32);
      den[j] += __shfl_xor(den[j], 16); den[j] += __shfl_xor(den[j], 32);
    }
    if (qw < 2) {
      short axa[4] = {ax.x, ax.y, ax.z, ax.w};
      short4 o;
      short ov[4];
      #pragma unroll
      for (int j = 0; j < 4; ++j) {
        int jj = qw * 4 + j;
        float aggr = num[jj] / (den[jj] + 1e-6f);
        float xp = bf2f(axa[j]) + aggr;
        ov[j] = f2bf(xp);
        sx[j] += xp; qx[j] += xp * xp;
      }
      o.x = ov[0]; o.y = ov[1]; o.z = ov[2]; o.w = ov[3];
      *(short4*)&outxh[(size_t)node * DD + c0] = o;
    }
  }

  __shared__ float lsX[4][128], lqX[4][128];
  if (qw < 2) {
    #pragma unroll
    for (int j = 0; j < 4; ++j) { lsX[w][fi * 8 + qw * 4 + j] = sx[j]; lqX[w][fi * 8 + qw * 4 + j] = qx[j]; }
  }
  __syncthreads();
  if (t < 128) {
    float a = lsX[0][t] + lsX[1][t] + lsX[2][t] + lsX[3][t];
    float b = lqX[0][t] + lqX[1][t] + lqX[2][t] + lqX[3][t];
    pX[(size_t)blockIdx.x * 256 + t] = a;
    pX[(size_t)blockIdx.x * 256 + 128 + t] = b;
  }
}

// reduce partials -> folded BN affine: stats[c]=scale, stats[128+c]=shift
__global__ __launch_bounds__(256) void k_reduce(const float* __restrict__ part, int nblk, float invcnt,
                                                const float* __restrict__ gamma, const float* __restrict__ beta,
                                                float* __restrict__ stats) {
  int c = blockIdx.x, t = threadIdx.x;
  float a = 0.f, b = 0.f;
  for (int k = t; k < nblk; k += 256) {
    a += part[(size_t)k * 256 + c];
    b += part[(size_t)k * 256 + 128 + c];
  }
  #pragma unroll
  for (int o = 32; o > 0; o >>= 1) { a += __shfl_down(a, o); b += __shfl_down(b, o); }
  __shared__ float ra[4], rb[4];
  int l = t & 63, w = t >> 6;
  if (l == 0) { ra[w] = a; rb[w] = b; }
  __syncthreads();
  if (t == 0) {
    a = ra[0] + ra[1] + ra[2] + ra[3];
    b = rb[0] + rb[1] + rb[2] + rb[3];
    float mean = a * invcnt;
    float var = b * invcnt - mean * mean;   // biased variance
    float istd = rsqrtf(var + 1e-5f);
    float scale = gamma[c] * istd;
    stats[c] = scale;
    stats[128 + c] = beta[c] - mean * scale;
  }
}

// ---------------- finalize x: bf16 x_pre -> BN+ReLU -> f32 out ----------------
__global__ __launch_bounds__(256) void k_xfinal(const short* __restrict__ vh, const float* __restrict__ st,
                                                float* __restrict__ out, size_t n8) {
  size_t i = (size_t)blockIdx.x * 256 + threadIdx.x;
  if (i >= n8) return;
  bf16x8 u = *(const bf16x8*)&vh[i * 8];
  int f0 = (int)((i * 8) & 127);
  float4 s0 = *(const float4*)&st[f0], s1 = *(const float4*)&st[f0 + 4];
  float4 h0 = *(const float4*)&st[128 + f0], h1 = *(const float4*)&st[128 + f0 + 4];
  float4 a, b;
  a.x = fmaxf(0.f, bf2f(u[0]) * s0.x + h0.x);
  a.y = fmaxf(0.f, bf2f(u[1]) * s0.y + h0.y);
  a.z = fmaxf(0.f, bf2f(u[2]) * s0.z + h0.z);
  a.w = fmaxf(0.f, bf2f(u[3]) * s0.w + h0.w);
  b.x = fmaxf(0.f, bf2f(u[4]) * s1.x + h1.x);
  b.y = fmaxf(0.f, bf2f(u[5]) * s1.y + h1.y);
  b.z = fmaxf(0.f, bf2f(u[6]) * s1.z + h1.z);
  b.w = fmaxf(0.f, bf2f(u[7]) * s1.w + h1.w);
  *(float4*)&out[i * 8] = a;
  *(float4*)&out[i * 8 + 4] = b;
}

extern "C" void kernel_launch(void* const* d_in, const int* in_sizes, int n_in,
                              void* d_out, int out_size, void* d_ws, size_t ws_size,
                              hipStream_t stream) {
  const float* x  = (const float*)d_in[0];
  const float* e  = (const float*)d_in[1];
  const int*   ei = (const int*)d_in[2];
  const float* WA = (const float*)d_in[3];  const float* bA = (const float*)d_in[4];
  const float* WB = (const float*)d_in[5];  const float* bB = (const float*)d_in[6];
  const float* WC = (const float*)d_in[7];  const float* bC = (const float*)d_in[8];
  const float* WD = (const float*)d_in[9];  const float* bD = (const float*)d_in[10];
  const float* WE = (const float*)d_in[11]; const float* bE = (const float*)d_in[12];
  const float* gx = (const float*)d_in[13]; const float* bx = (const float*)d_in[14];
  const float* ge = (const float*)d_in[15]; const float* be = (const float*)d_in[16];

  int N = in_sizes[0] / DD;
  int E = in_sizes[2] / 2;
  const int* srcI = ei;       // edge_index[0]
  const int* dstI = ei + E;   // edge_index[1]

  float* outx = (float*)d_out;
  float* oute = (float*)d_out + (size_t)N * DD;

  int ntilesE = (E + 63) / 64;

  char* wp = (char*)d_ws;
  auto alloc = [&](size_t sz) { char* p = wp; wp += (sz + 255) & ~(size_t)255; return p; };
  short* Axh    = (short*)alloc((size_t)N * DD * 2);
  short* Bxh    = (short*)alloc((size_t)N * DD * 2);
  short* Dxh    = (short*)alloc((size_t)N * DD * 2);
  short* Exh    = (short*)alloc((size_t)N * DD * 2);
  short* eijS   = (short*)alloc((size_t)E * DD * 2);
  short* outxh  = (short*)alloc((size_t)N * DD * 2);
  int*   deg    = (int*)alloc((size_t)N * 4);
  int*   off    = (int*)alloc((size_t)N * 4);
  int*   cursor = (int*)alloc((size_t)N * 4);
  int*   totals = (int*)alloc(1024);
  int*   boff   = (int*)alloc(1024);
  int*   list   = (int*)alloc((size_t)E * 4);
  int*   srcS   = (int*)alloc((size_t)E * 4);
  int*   posOf  = (int*)alloc((size_t)E * 4);
  float* pE     = (float*)alloc((size_t)GE * 4 * 256 * 4);   // per-wave partials
  float* pX     = (float*)alloc((size_t)NB_G * 256 * 4);
  float* statsE = (float*)alloc(1024);
  float* statsX = (float*)alloc(1024);
  short* WtA    = (short*)alloc((size_t)DD * DD * 2);
  short* WtB    = (short*)alloc((size_t)DD * DD * 2);
  short* WtC    = (short*)alloc((size_t)DD * DD * 2);
  short* WtD    = (short*)alloc((size_t)DD * DD * 2);
  short* WtE    = (short*)alloc((size_t)DD * DD * 2);
  (void)ws_size; (void)n_in; (void)out_size;

  int nsb = (N + 255) / 256;

  k_prep<<<5 + nsb, 256, 0, stream>>>(WA, WB, WC, WD, WE, WtA, WtB, WtC, WtD, WtE, deg, N);
  k_hist<<<(E + 255) / 256, 256, 0, stream>>>(dstI, deg, E);
  k_scan1<<<nsb, 256, 0, stream>>>(deg, off, totals, N);
  k_scan2<<<1, 256, 0, stream>>>(totals, boff, nsb);
  k_scan3<<<nsb, 256, 0, stream>>>(off, boff, cursor, N);
  k_fill<<<(E + 255) / 256, 256, 0, stream>>>(dstI, srcI, cursor, list, srcS, posOf, E);

  k_nodegemm<<<(N + 63) / 64, 256, 0, stream>>>(x, WtA, bA, WtB, bB, WtD, bD, WtE, bE,
                                                Axh, Bxh, Dxh, Exh, N);
  k_edge<<<GE, 256, 0, stream>>>(e, WtC, bC, srcI, dstI, posOf, Dxh, Exh, eijS, pE, E, ntilesE);
  k_reduce<<<128, 256, 0, stream>>>(pE, GE * 4, 1.0f / (float)E, ge, be, statsE);

  k_gather<<<NB_G, 256, 0, stream>>>(off, deg, list, srcS, eijS, Bxh, Axh, statsE,
                                     outxh, oute, pX, N);
  k_reduce<<<128, 256, 0, stream>>>(pX, NB_G, 1.0f / (float)N, gx, bx, statsX);
  k_xfinal<<<(int)(((size_t)N * DD / 8 + 255) / 256), 256, 0, stream>>>(outxh, statsX, outx, (size_t)N * DD / 8);
}